// Round 1
// baseline (1660.352 us; speedup 1.0000x reference)
//
#include <hip/hip_runtime.h>
#include <hip/hip_bf16.h>
#include <cstdint>
#include <cstddef>

#define HEADS 16
#define HD 64
#define NT 49
#define NTOK 3136          // NT*HD
#define MROWS 100352       // 2048*49
#define KDIM 1024

typedef __attribute__((ext_vector_type(4))) float f32x4;
typedef __attribute__((ext_vector_type(8))) short bf16x8;
typedef __attribute__((ext_vector_type(4))) unsigned short u16x4;

__device__ __forceinline__ unsigned short f2b(float f) {
  __hip_bfloat16 h = __float2bfloat16(f);
  return *reinterpret_cast<unsigned short*>(&h);
}
__device__ __forceinline__ float b2f(unsigned short u) {
  union { unsigned int i; float f; } c; c.i = ((unsigned int)u) << 16; return c.f;
}

__device__ __forceinline__ void gload16(const unsigned short* g, void* l) {
  __builtin_amdgcn_global_load_lds(
      (const __attribute__((address_space(1))) void*)g,
      (__attribute__((address_space(3))) void*)l, 16, 0, 0);
}

__device__ __forceinline__ void bar() {
  asm volatile("" ::: "memory");
  __builtin_amdgcn_s_barrier();
  asm volatile("" ::: "memory");
}

// ---------------- fp32 -> bf16 convert ----------------
__global__ void cvt_f32_bf16(const float* __restrict__ s,
                             unsigned short* __restrict__ d, long n4) {
  long stride = (long)gridDim.x * blockDim.x;
  for (long i = blockIdx.x * (long)blockDim.x + threadIdx.x; i < n4; i += stride) {
    f32x4 v = reinterpret_cast<const f32x4*>(s)[i];
    u16x4 o;
    o.x = f2b(v.x); o.y = f2b(v.y); o.z = f2b(v.z); o.w = f2b(v.w);
    reinterpret_cast<u16x4*>(d)[i] = o;
  }
}

// ---------------- bf16 B^T GEMM, 256x256 tile, 8-wave, phase-split ----------------
// C[m,n] = sum_k A[m,k]*B[n,k] + bias[n]
// LDS: 2 dbuf x (A[256][64] + B[256][64]) bf16 = 128 KiB.
// Swizzle (T2): phys_slot16B = logical_slot ^ (row&7)  (involution).
//   write side: linear LDS dest, pre-swizzled GLOBAL source column (rule #21)
//   read side : fOff = ((ks*4+kg) ^ (lr&7)) * 8 shorts
// Pipeline (T3/T4): 2 K-tiles in flight, vmcnt(8) counted, never 0 in loop.
template<int EPI>
__global__ __launch_bounds__(512, 2)
void gemm_bt(const unsigned short* __restrict__ A,
             const unsigned short* __restrict__ B,
             const float* __restrict__ bias,
             void* __restrict__ Cout,
             const int nTilesN) {
  __shared__ __align__(16) unsigned short lds[2 * 2 * 256 * 64]; // 128 KiB

  const int nwg = gridDim.x;
  const int bid = blockIdx.x;
  const int cpx = nwg >> 3;                       // nwg % 8 == 0 (4704 / 1568)
  const int swz = (bid & 7) * cpx + (bid >> 3);   // XCD-contiguous chunks (T1)
  const int mt = swz / nTilesN;
  const int nt = swz - mt * nTilesN;
  const long mBase = (long)mt * 256;
  const int nBase = nt * 256;

  const int tid = threadIdx.x;
  const int lane = tid & 63;
  const int wid = tid >> 6;
  const int wr = wid >> 2;        // 0..1  (M half: 128 rows)
  const int wc = wid & 3;         // 0..3  (N quarter: 64 cols)
  const int lr = lane & 15;
  const int kg = lane >> 4;       // 0..3

  // staging: thread covers row (tid>>3), pre-swizzled 16B slot of that row
  const int rbase = tid >> 3;                          // 0..63
  const int c8 = (((tid & 7) ^ (rbase & 7)) << 3);     // shorts
  const unsigned short* aSrc = A + (size_t)(mBase + rbase) * KDIM + c8;
  const unsigned short* bSrc = B + (size_t)(nBase + rbase) * KDIM + c8;
  char* ldsB = (char*)lds;

  f32x4 acc[8][4] = {};

  // fragment ds_read offsets (shorts), swizzled
  const int aRow = (wr * 128 + lr) * 64;
  const int bRow = (wc * 64 + lr) * 64;
  int fOff[2];
#pragma unroll
  for (int ks = 0; ks < 2; ++ks)
    fOff[ks] = ((ks * 4 + kg) ^ (lr & 7)) << 3;

#define STAGE(buf, kt) do {                                         \
    char* dA = ldsB + (buf) * 65536 + tid * 16;                     \
    const unsigned short* sA = aSrc + (kt) * 64;                    \
    const unsigned short* sB = bSrc + (kt) * 64;                    \
    _Pragma("unroll")                                               \
    for (int j = 0; j < 4; ++j)                                     \
      gload16(sA + (size_t)j * 64 * KDIM, dA + j * 8192);           \
    _Pragma("unroll")                                               \
    for (int j = 0; j < 4; ++j)                                     \
      gload16(sB + (size_t)j * 64 * KDIM, dA + 32768 + j * 8192);   \
  } while (0)

  // prologue: tiles 0 and 1 in flight; wait tile 0 only
  STAGE(0, 0);
  STAGE(1, 1);
  asm volatile("s_waitcnt vmcnt(8)" ::: "memory");
  __builtin_amdgcn_sched_barrier(0);
  bar();

  for (int kt = 0; kt < KDIM / 64; ++kt) {
    const int cb = kt & 1;
    const unsigned short* As = lds + cb * 32768;
    const unsigned short* Bs = As + 16384;
    bf16x8 bfr[2][4];
#pragma unroll
    for (int q = 0; q < 4; ++q) {       // 4 phases x 16 MFMA
      bf16x8 af[2][2];
      if (q == 0) {
#pragma unroll
        for (int ks = 0; ks < 2; ++ks)
#pragma unroll
          for (int n = 0; n < 4; ++n)
            bfr[ks][n] = *reinterpret_cast<const bf16x8*>(
                Bs + bRow + n * 1024 + fOff[ks]);
      }
#pragma unroll
      for (int ks = 0; ks < 2; ++ks)
#pragma unroll
        for (int mm = 0; mm < 2; ++mm)
          af[ks][mm] = *reinterpret_cast<const bf16x8*>(
              As + aRow + (q * 2 + mm) * 1024 + fOff[ks]);
      bar();
      __builtin_amdgcn_s_setprio(1);
#pragma unroll
      for (int mm = 0; mm < 2; ++mm)
#pragma unroll
        for (int ks = 0; ks < 2; ++ks)
#pragma unroll
          for (int n = 0; n < 4; ++n)
            acc[q * 2 + mm][n] = __builtin_amdgcn_mfma_f32_16x16x32_bf16(
                af[ks][mm], bfr[ks][n], acc[q * 2 + mm][n], 0, 0, 0);
      __builtin_amdgcn_s_setprio(0);
      bar();
    }
    // all waves past phase barriers -> buf[cb] fully consumed; refill it
    if (kt < KDIM / 64 - 2) {
      STAGE(cb, kt + 2);
      asm volatile("s_waitcnt vmcnt(8)" ::: "memory");  // tile kt+1 landed
      __builtin_amdgcn_sched_barrier(0);
      bar();
    } else if (kt == KDIM / 64 - 2) {
      asm volatile("s_waitcnt vmcnt(0)" ::: "memory");  // drain last tile
      __builtin_amdgcn_sched_barrier(0);
      bar();
    }
  }
#undef STAGE

  if (EPI == 0) {
    unsigned short* qkvbuf = (unsigned short*)Cout;
#pragma unroll
    for (int m = 0; m < 8; ++m) {
      const int row0 = wr * 128 + m * 16 + kg * 4;
#pragma unroll
      for (int n = 0; n < 4; ++n) {
        const int col = nBase + wc * 64 + n * 16 + lr;
        const int which = col >> 10;
        const int head = (col >> 6) & 15;
        const int d = col & 63;
        const float bv = bias[col];
#pragma unroll
        for (int r = 0; r < 4; ++r) {
          const int gm = (int)mBase + row0 + r;
          const int w = gm / NT;
          const int t = gm - w * NT;
          float v = acc[m][n][r] + bv;
          if (which == 0) v *= 0.125f;
          qkvbuf[(((size_t)w * 3 + which) * HEADS + head) * NTOK + t * HD + d] =
              f2b(v);
        }
      }
    }
  } else {
    float* out = (float*)Cout;
#pragma unroll
    for (int m = 0; m < 8; ++m) {
      const int row0 = wr * 128 + m * 16 + kg * 4;
#pragma unroll
      for (int n = 0; n < 4; ++n) {
        const int col = nBase + wc * 64 + n * 16 + lr;
        const float bv = bias[col];
#pragma unroll
        for (int r = 0; r < 4; ++r) {
          const int gm = (int)mBase + row0 + r;
          out[(size_t)gm * KDIM + col] = acc[m][n][r] + bv;
        }
      }
    }
  }
}

// ---------------- window attention: 1 wave per (window, head), MFMA ----------------
#define PSTR 72   // P LDS stride (elements), 16B-aligned rows
#define VSTR 68   // V LDS stride (elements), 8B-aligned rows

__global__ __launch_bounds__(64)
void attn_mfma(const unsigned short* __restrict__ qkv,
               const float* __restrict__ mask,
               const float* __restrict__ bias_table,
               unsigned short* __restrict__ aout) {
  const int blk = blockIdx.x;
  const int w = blk >> 4;
  const int h = blk & 15;
  const int lane = threadIdx.x;
  const int lr = lane & 15;
  const int kg = lane >> 4;

  __shared__ __align__(16) unsigned short Plds[64 * PSTR];
  __shared__ __align__(16) unsigned short Vlds[64 * VSTR];

  const unsigned short* qp = qkv + (((size_t)w * 3 + 0) * HEADS + h) * NTOK;
  const unsigned short* kp = qp + (size_t)HEADS * NTOK;
  const unsigned short* vp = qp + (size_t)2 * HEADS * NTOK;
  const float* mrow = mask + (size_t)(w & 63) * (NT * NT);

  // ---- stage V into LDS (rows t<49), zero pad rows 49..63 ----
#pragma unroll
  for (int i = 0; i < 13; ++i) {
    const int idx = i * 64 + lane;          // u16x4 chunk index, 784 total
    if (idx < 784) {
      const int t = idx >> 4, c4 = (idx & 15) * 4;
      u16x4 vv = *reinterpret_cast<const u16x4*>(vp + t * HD + c4);
      *reinterpret_cast<u16x4*>(&Vlds[t * VSTR + c4]) = vv;
    }
  }
  {
    unsigned int* z = reinterpret_cast<unsigned int*>(&Vlds[49 * VSTR]);
#pragma unroll
    for (int i = 0; i < 8; ++i) {
      const int idx = i * 64 + lane;        // 15*68/2 = 510 words
      if (idx < 510) z[idx] = 0u;
    }
  }

  // ---- accumulator preload: rel-bias + window mask (C-in of QK^T) ----
  f32x4 acc[4][4];
  {
    int ibv[4], jbv[4];
#pragma unroll
    for (int n = 0; n < 4; ++n) {
      const int b = n * 16 + lr;
      ibv[n] = b / 7; jbv[n] = b % 7;
    }
#pragma unroll
    for (int m = 0; m < 4; ++m) {
#pragma unroll
      for (int r = 0; r < 4; ++r) {
        const int a = m * 16 + kg * 4 + r;
        const int ia = a / 7, ja = a % 7;
#pragma unroll
        for (int n = 0; n < 4; ++n) {
          const int b = n * 16 + lr;
          float v;
          if (b >= NT) v = -1e30f;
          else if (a >= NT) v = 0.f;
          else v = bias_table[((ia - ibv[n] + 6) * 13 + (ja - jbv[n] + 6)) * HEADS + h]
                 + mrow[a * NT + b];
          acc[m][n][r] = v;
        }
      }
    }
  }

  // ---- QK^T: direct global fragment loads ----
#pragma unroll
  for (int ks = 0; ks < 2; ++ks) {
    bf16x8 af[4], bfr[4];
#pragma unroll
    for (int m = 0; m < 4; ++m) {
      int row = m * 16 + lr; if (row > 48) row = 48;
      af[m] = *reinterpret_cast<const bf16x8*>(qp + row * HD + ks * 32 + kg * 8);
    }
#pragma unroll
    for (int n = 0; n < 4; ++n) {
      int row = n * 16 + lr; if (row > 48) row = 48;
      bfr[n] = *reinterpret_cast<const bf16x8*>(kp + row * HD + ks * 32 + kg * 8);
    }
#pragma unroll
    for (int m = 0; m < 4; ++m)
#pragma unroll
      for (int n = 0; n < 4; ++n)
        acc[m][n] = __builtin_amdgcn_mfma_f32_16x16x32_bf16(
            af[m], bfr[n], acc[m][n], 0, 0, 0);
  }

  // ---- in-register softmax: row a lives in the 16 lanes sharing kg ----
#pragma unroll
  for (int m = 0; m < 4; ++m) {
#pragma unroll
    for (int r = 0; r < 4; ++r) {
      float mx = fmaxf(fmaxf(acc[m][0][r], acc[m][1][r]),
                       fmaxf(acc[m][2][r], acc[m][3][r]));
      mx = fmaxf(mx, __shfl_xor(mx, 1));
      mx = fmaxf(mx, __shfl_xor(mx, 2));
      mx = fmaxf(mx, __shfl_xor(mx, 4));
      mx = fmaxf(mx, __shfl_xor(mx, 8));
      float s = 0.f;
#pragma unroll
      for (int n = 0; n < 4; ++n) {
        const float e = __expf(acc[m][n][r] - mx);
        acc[m][n][r] = e;
        s += e;
      }
      s += __shfl_xor(s, 1);
      s += __shfl_xor(s, 2);
      s += __shfl_xor(s, 4);
      s += __shfl_xor(s, 8);
      const float si = 1.0f / s;
#pragma unroll
      for (int n = 0; n < 4; ++n) acc[m][n][r] *= si;
    }
  }
  __syncthreads();   // V staging complete before PV reads; order P writes

  // ---- P (normalized, bf16) -> LDS ----
#pragma unroll
  for (int m = 0; m < 4; ++m)
#pragma unroll
    for (int n = 0; n < 4; ++n)
#pragma unroll
      for (int r = 0; r < 4; ++r)
        Plds[(m * 16 + kg * 4 + r) * PSTR + n * 16 + lr] = f2b(acc[m][n][r]);
  __syncthreads();

  // ---- PV: A = P (LDS b128), B = V^T (LDS scalar column reads) ----
  f32x4 acc2[4][4] = {};
#pragma unroll
  for (int ks = 0; ks < 2; ++ks) {
    bf16x8 pf[4], vf[4];
#pragma unroll
    for (int m = 0; m < 4; ++m)
      pf[m] = *reinterpret_cast<const bf16x8*>(
          &Plds[(m * 16 + lr) * PSTR + ks * 32 + kg * 8]);
#pragma unroll
    for (int n = 0; n < 4; ++n) {
      union { bf16x8 v; unsigned short u[8]; } vu;
#pragma unroll
      for (int j = 0; j < 8; ++j)
        vu.u[j] = Vlds[(ks * 32 + kg * 8 + j) * VSTR + n * 16 + lr];
      vf[n] = vu.v;
    }
#pragma unroll
    for (int m = 0; m < 4; ++m)
#pragma unroll
      for (int n = 0; n < 4; ++n)
        acc2[m][n] = __builtin_amdgcn_mfma_f32_16x16x32_bf16(
            pf[m], vf[n], acc2[m][n], 0, 0, 0);
  }

  // ---- store O rows a<49, bf16 [w*49+a][h*64+d] ----
#pragma unroll
  for (int m = 0; m < 4; ++m) {
#pragma unroll
    for (int r = 0; r < 4; ++r) {
      const int a = m * 16 + kg * 4 + r;
      if (a >= NT) continue;
#pragma unroll
      for (int n = 0; n < 4; ++n) {
        const int d = n * 16 + lr;
        aout[((size_t)(w * NT + a)) * KDIM + h * HD + d] = f2b(acc2[m][n][r]);
      }
    }
  }
}

extern "C" void kernel_launch(void* const* d_in, const int* in_sizes, int n_in,
                              void* d_out, int out_size, void* d_ws, size_t ws_size,
                              hipStream_t stream) {
  const float* x          = (const float*)d_in[0];
  const float* attn_mask  = (const float*)d_in[1];
  const float* qkv_w      = (const float*)d_in[2];
  const float* qkv_b      = (const float*)d_in[3];
  const float* proj_w     = (const float*)d_in[4];
  const float* proj_b     = (const float*)d_in[5];
  const float* bias_table = (const float*)d_in[6];
  float* out = (float*)d_out;

  char* ws = (char*)d_ws;
  const size_t xbf_bytes = (size_t)MROWS * KDIM * 2;
  unsigned short* xbf      = (unsigned short*)ws;
  unsigned short* qkvw_bf  = (unsigned short*)(ws + xbf_bytes);
  unsigned short* projw_bf = qkvw_bf + 3072 * 1024;
  unsigned short* qkvbuf   = (unsigned short*)(ws + xbf_bytes + 8388608);
  unsigned short* aout     = xbf;  // x_bf16 dead after QKV GEMM; reuse

  cvt_f32_bf16<<<8192, 256, 0, stream>>>(x, xbf, (long)MROWS * KDIM / 4);
  cvt_f32_bf16<<<3072, 256, 0, stream>>>(qkv_w, qkvw_bf, (long)3072 * 1024 / 4);
  cvt_f32_bf16<<<1024, 256, 0, stream>>>(proj_w, projw_bf, (long)1024 * 1024 / 4);

  // 256x256 tiles: M tiles = 100352/256 = 392
  gemm_bt<0><<<392 * 12, 512, 0, stream>>>(xbf, qkvw_bf, qkv_b, (void*)qkvbuf, 12);

  attn_mfma<<<2048 * HEADS, 64, 0, stream>>>(qkvbuf, attn_mask, bias_table, aout);

  gemm_bt<1><<<392 * 4, 512, 0, stream>>>(aout, projw_bf, proj_b, (void*)out, 4);
}

// Round 2
// 1600.378 us; speedup vs baseline: 1.0375x; 1.0375x over previous
//
#include <hip/hip_runtime.h>
#include <hip/hip_bf16.h>
#include <cstdint>
#include <cstddef>

#define HEADS 16
#define HD 64
#define NT 49
#define NTOK 3136          // NT*HD
#define MROWS 100352       // 2048*49
#define KDIM 1024

typedef __attribute__((ext_vector_type(4))) float f32x4;
typedef __attribute__((ext_vector_type(8))) short bf16x8;
typedef __attribute__((ext_vector_type(4))) unsigned short u16x4;

__device__ __forceinline__ unsigned short f2b(float f) {
  __hip_bfloat16 h = __float2bfloat16(f);
  return *reinterpret_cast<unsigned short*>(&h);
}
__device__ __forceinline__ float b2f(unsigned short u) {
  union { unsigned int i; float f; } c; c.i = ((unsigned int)u) << 16; return c.f;
}

__device__ __forceinline__ void gload16(const unsigned short* g, void* l) {
  __builtin_amdgcn_global_load_lds(
      (const __attribute__((address_space(1))) void*)g,
      (__attribute__((address_space(3))) void*)l, 16, 0, 0);
}

__device__ __forceinline__ void bar() {
  asm volatile("" ::: "memory");
  __builtin_amdgcn_s_barrier();
  asm volatile("" ::: "memory");
}

// ---------------- fp32 -> bf16 convert ----------------
__global__ void cvt_f32_bf16(const float* __restrict__ s,
                             unsigned short* __restrict__ d, long n4) {
  long stride = (long)gridDim.x * blockDim.x;
  for (long i = blockIdx.x * (long)blockDim.x + threadIdx.x; i < n4; i += stride) {
    f32x4 v = reinterpret_cast<const f32x4*>(s)[i];
    u16x4 o;
    o.x = f2b(v.x); o.y = f2b(v.y); o.z = f2b(v.z); o.w = f2b(v.w);
    reinterpret_cast<u16x4*>(d)[i] = o;
  }
}

// ---------------- bf16 B^T GEMM, 256x256 tile, 8-wave, pipelined phases ----------------
// C[m,n] = sum_k A[m,k]*B[n,k] + bias[n]
// LDS: 2 dbuf x (A[256][64] + B[256][64]) bf16 = 128 KiB.
// Swizzle (T2): phys_slot16B = logical_slot ^ (row&7) (involution):
//   write: linear LDS dest, pre-swizzled GLOBAL source column (rule #21)
//   read : fOff = ((ks*4+kg) ^ (lr&7)) * 8 shorts
// Schedule: 4 phases/K-tile split by (ks, m-half), 16 MFMA each; the ds_reads
// for phase q+1 are issued INSIDE cluster q (before its MFMAs) so the LDS pipe
// overlaps the matrix pipe. Staging is a lump at the K-tile boundary with
// counted vmcnt(8) (wait target was issued one full K-tile earlier).
template<int EPI>
__global__ __launch_bounds__(512, 2)
void gemm_bt(const unsigned short* __restrict__ A,
             const unsigned short* __restrict__ B,
             const float* __restrict__ bias,
             void* __restrict__ Cout,
             const int nTilesN) {
  __shared__ __align__(16) unsigned short lds[2 * 2 * 256 * 64]; // 128 KiB

  const int nwg = gridDim.x;
  const int bid = blockIdx.x;
  const int cpx = nwg >> 3;                       // nwg % 8 == 0 (4704 / 1568)
  const int swz = (bid & 7) * cpx + (bid >> 3);   // XCD-contiguous chunks (T1)
  const int mt = swz / nTilesN;
  const int nt = swz - mt * nTilesN;
  const long mBase = (long)mt * 256;
  const int nBase = nt * 256;

  const int tid = threadIdx.x;
  const int lane = tid & 63;
  const int wid = tid >> 6;
  const int wr = wid >> 2;        // 0..1  (M half: 128 rows)
  const int wc = wid & 3;         // 0..3  (N quarter: 64 cols)
  const int lr = lane & 15;
  const int kg = lane >> 4;       // 0..3

  // staging: thread covers row (tid>>3), pre-swizzled 16B slot of that row
  const int rbase = tid >> 3;                          // 0..63
  const int c8 = (((tid & 7) ^ (rbase & 7)) << 3);     // shorts
  const unsigned short* aSrc = A + (size_t)(mBase + rbase) * KDIM + c8;
  const unsigned short* bSrc = B + (size_t)(nBase + rbase) * KDIM + c8;
  char* ldsB = (char*)lds;

  f32x4 acc[8][4] = {};

  const int aRow = (wr * 128 + lr) * 64;
  const int bRow = (wc * 64 + lr) * 64;
  const int fOff0 = ((0 * 4 + kg) ^ (lr & 7)) << 3;
  const int fOff1 = ((1 * 4 + kg) ^ (lr & 7)) << 3;

#define STAGE(buf, kt) do {                                         \
    char* dA = ldsB + (buf) * 65536 + tid * 16;                     \
    const unsigned short* sA = aSrc + (kt) * 64;                    \
    const unsigned short* sB = bSrc + (kt) * 64;                    \
    _Pragma("unroll")                                               \
    for (int j = 0; j < 4; ++j)                                     \
      gload16(sA + (size_t)j * 64 * KDIM, dA + j * 8192);           \
    _Pragma("unroll")                                               \
    for (int j = 0; j < 4; ++j)                                     \
      gload16(sB + (size_t)j * 64 * KDIM, dA + 32768 + j * 8192);   \
  } while (0)

  // prologue: tiles 0 and 1 in flight; wait tile 0 only
  STAGE(0, 0);
  STAGE(1, 1);
  asm volatile("s_waitcnt vmcnt(8)" ::: "memory");
  __builtin_amdgcn_sched_barrier(0);
  bar();

  for (int kt = 0; kt < KDIM / 64; ++kt) {
    const int cb = kt & 1;
    const unsigned short* As = lds + cb * 32768;
    const unsigned short* Bs = As + 16384;

    bf16x8 a0[4], a1[4], a2[4], a3[4], b0[4], b1[4];

    // ---- P0 reads (unhidden: first touch of this buffer) ----
#pragma unroll
    for (int j = 0; j < 4; ++j)
      a0[j] = *reinterpret_cast<const bf16x8*>(As + aRow + j * 1024 + fOff0);
#pragma unroll
    for (int n = 0; n < 4; ++n)
      b0[n] = *reinterpret_cast<const bf16x8*>(Bs + bRow + n * 1024 + fOff0);

    // ---- cluster 0: prefetch P1 frags, MFMA P0 (m0-3 x ks0) ----
    __builtin_amdgcn_s_setprio(1);
#pragma unroll
    for (int j = 0; j < 4; ++j)
      a1[j] = *reinterpret_cast<const bf16x8*>(As + aRow + (4 + j) * 1024 + fOff0);
#pragma unroll
    for (int j = 0; j < 4; ++j)
#pragma unroll
      for (int n = 0; n < 4; ++n)
        acc[j][n] = __builtin_amdgcn_mfma_f32_16x16x32_bf16(
            a0[j], b0[n], acc[j][n], 0, 0, 0);
    __builtin_amdgcn_s_setprio(0);
    bar();

    // ---- cluster 1: prefetch P2 frags, MFMA P1 (m4-7 x ks0) ----
    __builtin_amdgcn_s_setprio(1);
#pragma unroll
    for (int j = 0; j < 4; ++j)
      a2[j] = *reinterpret_cast<const bf16x8*>(As + aRow + j * 1024 + fOff1);
#pragma unroll
    for (int n = 0; n < 4; ++n)
      b1[n] = *reinterpret_cast<const bf16x8*>(Bs + bRow + n * 1024 + fOff1);
#pragma unroll
    for (int j = 0; j < 4; ++j)
#pragma unroll
      for (int n = 0; n < 4; ++n)
        acc[4 + j][n] = __builtin_amdgcn_mfma_f32_16x16x32_bf16(
            a1[j], b0[n], acc[4 + j][n], 0, 0, 0);
    __builtin_amdgcn_s_setprio(0);
    bar();

    // ---- cluster 2: prefetch P3 frags, MFMA P2 (m0-3 x ks1) ----
    __builtin_amdgcn_s_setprio(1);
#pragma unroll
    for (int j = 0; j < 4; ++j)
      a3[j] = *reinterpret_cast<const bf16x8*>(As + aRow + (4 + j) * 1024 + fOff1);
#pragma unroll
    for (int j = 0; j < 4; ++j)
#pragma unroll
      for (int n = 0; n < 4; ++n)
        acc[j][n] = __builtin_amdgcn_mfma_f32_16x16x32_bf16(
            a2[j], b1[n], acc[j][n], 0, 0, 0);
    __builtin_amdgcn_s_setprio(0);
    bar();

    // ---- cluster 3: MFMA P3 (m4-7 x ks1) ----
    __builtin_amdgcn_s_setprio(1);
#pragma unroll
    for (int j = 0; j < 4; ++j)
#pragma unroll
      for (int n = 0; n < 4; ++n)
        acc[4 + j][n] = __builtin_amdgcn_mfma_f32_16x16x32_bf16(
            a3[j], b1[n], acc[4 + j][n], 0, 0, 0);
    __builtin_amdgcn_s_setprio(0);
    bar();   // all waves done reading buf[cb] -> safe to restage it

    if (kt < KDIM / 64 - 2) {
      STAGE(cb, kt + 2);
      asm volatile("s_waitcnt vmcnt(8)" ::: "memory");  // tile kt+1 landed
      __builtin_amdgcn_sched_barrier(0);
      bar();
    } else if (kt == KDIM / 64 - 2) {
      asm volatile("s_waitcnt vmcnt(0)" ::: "memory");  // drain last tile
      __builtin_amdgcn_sched_barrier(0);
      bar();
    }
  }
#undef STAGE

  if (EPI == 0) {
    unsigned short* qkvbuf = (unsigned short*)Cout;
#pragma unroll
    for (int m = 0; m < 8; ++m) {
      const int row0 = wr * 128 + m * 16 + kg * 4;
#pragma unroll
      for (int n = 0; n < 4; ++n) {
        const int col = nBase + wc * 64 + n * 16 + lr;
        const int which = col >> 10;
        const int head = (col >> 6) & 15;
        const int d = col & 63;
        const float bv = bias[col];
#pragma unroll
        for (int r = 0; r < 4; ++r) {
          const int gm = (int)mBase + row0 + r;
          const int w = gm / NT;
          const int t = gm - w * NT;
          float v = acc[m][n][r] + bv;
          if (which == 0) v *= 0.125f;
          qkvbuf[(((size_t)w * 3 + which) * HEADS + head) * NTOK + t * HD + d] =
              f2b(v);
        }
      }
    }
  } else {
    float* out = (float*)Cout;
#pragma unroll
    for (int m = 0; m < 8; ++m) {
      const int row0 = wr * 128 + m * 16 + kg * 4;
#pragma unroll
      for (int n = 0; n < 4; ++n) {
        const int col = nBase + wc * 64 + n * 16 + lr;
        const float bv = bias[col];
#pragma unroll
        for (int r = 0; r < 4; ++r) {
          const int gm = (int)mBase + row0 + r;
          out[(size_t)gm * KDIM + col] = acc[m][n][r] + bv;
        }
      }
    }
  }
}

// ---------------- window attention: 1 wave per (window, head), MFMA ----------------
#define PSTR 72   // P LDS stride (elements), 16B-aligned rows
#define VSTR 68   // V LDS stride (elements), 8B-aligned rows

__global__ __launch_bounds__(64)
void attn_mfma(const unsigned short* __restrict__ qkv,
               const float* __restrict__ mask,
               const float* __restrict__ bias_table,
               unsigned short* __restrict__ aout) {
  const int blk = blockIdx.x;
  const int w = blk >> 4;
  const int h = blk & 15;
  const int lane = threadIdx.x;
  const int lr = lane & 15;
  const int kg = lane >> 4;

  __shared__ __align__(16) unsigned short Plds[64 * PSTR];
  __shared__ __align__(16) unsigned short Vlds[64 * VSTR];

  const unsigned short* qp = qkv + (((size_t)w * 3 + 0) * HEADS + h) * NTOK;
  const unsigned short* kp = qp + (size_t)HEADS * NTOK;
  const unsigned short* vp = qp + (size_t)2 * HEADS * NTOK;
  const float* mrow = mask + (size_t)(w & 63) * (NT * NT);

  // ---- stage V into LDS (rows t<49), zero pad rows 49..63 ----
#pragma unroll
  for (int i = 0; i < 13; ++i) {
    const int idx = i * 64 + lane;          // u16x4 chunk index, 784 total
    if (idx < 784) {
      const int t = idx >> 4, c4 = (idx & 15) * 4;
      u16x4 vv = *reinterpret_cast<const u16x4*>(vp + t * HD + c4);
      *reinterpret_cast<u16x4*>(&Vlds[t * VSTR + c4]) = vv;
    }
  }
  {
    unsigned int* z = reinterpret_cast<unsigned int*>(&Vlds[49 * VSTR]);
#pragma unroll
    for (int i = 0; i < 8; ++i) {
      const int idx = i * 64 + lane;        // 15*68/2 = 510 words
      if (idx < 510) z[idx] = 0u;
    }
  }

  // ---- accumulator preload: rel-bias + window mask (C-in of QK^T) ----
  f32x4 acc[4][4];
  {
    int ibv[4], jbv[4];
#pragma unroll
    for (int n = 0; n < 4; ++n) {
      const int b = n * 16 + lr;
      ibv[n] = b / 7; jbv[n] = b % 7;
    }
#pragma unroll
    for (int m = 0; m < 4; ++m) {
#pragma unroll
      for (int r = 0; r < 4; ++r) {
        const int a = m * 16 + kg * 4 + r;
        const int ia = a / 7, ja = a % 7;
#pragma unroll
        for (int n = 0; n < 4; ++n) {
          const int b = n * 16 + lr;
          float v;
          if (b >= NT) v = -1e30f;
          else if (a >= NT) v = 0.f;
          else v = bias_table[((ia - ibv[n] + 6) * 13 + (ja - jbv[n] + 6)) * HEADS + h]
                 + mrow[a * NT + b];
          acc[m][n][r] = v;
        }
      }
    }
  }

  // ---- QK^T: direct global fragment loads ----
#pragma unroll
  for (int ks = 0; ks < 2; ++ks) {
    bf16x8 af[4], bfr[4];
#pragma unroll
    for (int m = 0; m < 4; ++m) {
      int row = m * 16 + lr; if (row > 48) row = 48;
      af[m] = *reinterpret_cast<const bf16x8*>(qp + row * HD + ks * 32 + kg * 8);
    }
#pragma unroll
    for (int n = 0; n < 4; ++n) {
      int row = n * 16 + lr; if (row > 48) row = 48;
      bfr[n] = *reinterpret_cast<const bf16x8*>(kp + row * HD + ks * 32 + kg * 8);
    }
#pragma unroll
    for (int m = 0; m < 4; ++m)
#pragma unroll
      for (int n = 0; n < 4; ++n)
        acc[m][n] = __builtin_amdgcn_mfma_f32_16x16x32_bf16(
            af[m], bfr[n], acc[m][n], 0, 0, 0);
  }

  // ---- in-register softmax: row a lives in the 16 lanes sharing kg ----
#pragma unroll
  for (int m = 0; m < 4; ++m) {
#pragma unroll
    for (int r = 0; r < 4; ++r) {
      float mx = fmaxf(fmaxf(acc[m][0][r], acc[m][1][r]),
                       fmaxf(acc[m][2][r], acc[m][3][r]));
      mx = fmaxf(mx, __shfl_xor(mx, 1));
      mx = fmaxf(mx, __shfl_xor(mx, 2));
      mx = fmaxf(mx, __shfl_xor(mx, 4));
      mx = fmaxf(mx, __shfl_xor(mx, 8));
      float s = 0.f;
#pragma unroll
      for (int n = 0; n < 4; ++n) {
        const float e = __expf(acc[m][n][r] - mx);
        acc[m][n][r] = e;
        s += e;
      }
      s += __shfl_xor(s, 1);
      s += __shfl_xor(s, 2);
      s += __shfl_xor(s, 4);
      s += __shfl_xor(s, 8);
      const float si = 1.0f / s;
#pragma unroll
      for (int n = 0; n < 4; ++n) acc[m][n][r] *= si;
    }
  }
  __syncthreads();   // V staging complete before PV reads; order P writes

  // ---- P (normalized, bf16) -> LDS ----
#pragma unroll
  for (int m = 0; m < 4; ++m)
#pragma unroll
    for (int n = 0; n < 4; ++n)
#pragma unroll
      for (int r = 0; r < 4; ++r)
        Plds[(m * 16 + kg * 4 + r) * PSTR + n * 16 + lr] = f2b(acc[m][n][r]);
  __syncthreads();

  // ---- PV: A = P (LDS b128), B = V^T (LDS scalar column reads) ----
  f32x4 acc2[4][4] = {};
#pragma unroll
  for (int ks = 0; ks < 2; ++ks) {
    bf16x8 pf[4], vf[4];
#pragma unroll
    for (int m = 0; m < 4; ++m)
      pf[m] = *reinterpret_cast<const bf16x8*>(
          &Plds[(m * 16 + lr) * PSTR + ks * 32 + kg * 8]);
#pragma unroll
    for (int n = 0; n < 4; ++n) {
      union { bf16x8 v; unsigned short u[8]; } vu;
#pragma unroll
      for (int j = 0; j < 8; ++j)
        vu.u[j] = Vlds[(ks * 32 + kg * 8 + j) * VSTR + n * 16 + lr];
      vf[n] = vu.v;
    }
#pragma unroll
    for (int m = 0; m < 4; ++m)
#pragma unroll
      for (int n = 0; n < 4; ++n)
        acc2[m][n] = __builtin_amdgcn_mfma_f32_16x16x32_bf16(
            pf[m], vf[n], acc2[m][n], 0, 0, 0);
  }

  // ---- store O rows a<49, bf16 [w*49+a][h*64+d] ----
#pragma unroll
  for (int m = 0; m < 4; ++m) {
#pragma unroll
    for (int r = 0; r < 4; ++r) {
      const int a = m * 16 + kg * 4 + r;
      if (a >= NT) continue;
#pragma unroll
      for (int n = 0; n < 4; ++n) {
        const int d = n * 16 + lr;
        aout[((size_t)(w * NT + a)) * KDIM + h * HD + d] = f2b(acc2[m][n][r]);
      }
    }
  }
}

extern "C" void kernel_launch(void* const* d_in, const int* in_sizes, int n_in,
                              void* d_out, int out_size, void* d_ws, size_t ws_size,
                              hipStream_t stream) {
  const float* x          = (const float*)d_in[0];
  const float* attn_mask  = (const float*)d_in[1];
  const float* qkv_w      = (const float*)d_in[2];
  const float* qkv_b      = (const float*)d_in[3];
  const float* proj_w     = (const float*)d_in[4];
  const float* proj_b     = (const float*)d_in[5];
  const float* bias_table = (const float*)d_in[6];
  float* out = (float*)d_out;

  char* ws = (char*)d_ws;
  const size_t xbf_bytes = (size_t)MROWS * KDIM * 2;
  unsigned short* xbf      = (unsigned short*)ws;
  unsigned short* qkvw_bf  = (unsigned short*)(ws + xbf_bytes);
  unsigned short* projw_bf = qkvw_bf + 3072 * 1024;
  unsigned short* qkvbuf   = (unsigned short*)(ws + xbf_bytes + 8388608);
  unsigned short* aout     = xbf;  // x_bf16 dead after QKV GEMM; reuse

  cvt_f32_bf16<<<8192, 256, 0, stream>>>(x, xbf, (long)MROWS * KDIM / 4);
  cvt_f32_bf16<<<3072, 256, 0, stream>>>(qkv_w, qkvw_bf, (long)3072 * 1024 / 4);
  cvt_f32_bf16<<<1024, 256, 0, stream>>>(proj_w, projw_bf, (long)1024 * 1024 / 4);

  // 256x256 tiles: M tiles = 100352/256 = 392
  gemm_bt<0><<<392 * 12, 512, 0, stream>>>(xbf, qkvw_bf, qkv_b, (void*)qkvbuf, 12);

  attn_mfma<<<2048 * HEADS, 64, 0, stream>>>(qkvbuf, attn_mask, bias_table, aout);

  gemm_bt<1><<<392 * 4, 512, 0, stream>>>(aout, projw_bf, proj_b, (void*)out, 4);
}

// Round 3
// 1508.970 us; speedup vs baseline: 1.1003x; 1.0606x over previous
//
#include <hip/hip_runtime.h>
#include <hip/hip_bf16.h>
#include <cstdint>
#include <cstddef>

#define HEADS 16
#define HD 64
#define NT 49
#define NTOK 3136          // NT*HD
#define MROWS 100352       // 2048*49
#define KDIM 1024

typedef __attribute__((ext_vector_type(4))) float f32x4;
typedef __attribute__((ext_vector_type(8))) short bf16x8;
typedef __attribute__((ext_vector_type(4))) unsigned short u16x4;

__device__ __forceinline__ unsigned short f2b(float f) {
  __hip_bfloat16 h = __float2bfloat16(f);
  return *reinterpret_cast<unsigned short*>(&h);
}
__device__ __forceinline__ float b2f(unsigned short u) {
  union { unsigned int i; float f; } c; c.i = ((unsigned int)u) << 16; return c.f;
}

__device__ __forceinline__ void gload16(const unsigned short* g, void* l) {
  __builtin_amdgcn_global_load_lds(
      (const __attribute__((address_space(1))) void*)g,
      (__attribute__((address_space(3))) void*)l, 16, 0, 0);
}

__device__ __forceinline__ void bar() {
  asm volatile("" ::: "memory");
  __builtin_amdgcn_s_barrier();
  asm volatile("" ::: "memory");
}

// ---------------- fp32 -> bf16 convert ----------------
__global__ void cvt_f32_bf16(const float* __restrict__ s,
                             unsigned short* __restrict__ d, long n4) {
  long stride = (long)gridDim.x * blockDim.x;
  for (long i = blockIdx.x * (long)blockDim.x + threadIdx.x; i < n4; i += stride) {
    f32x4 v = reinterpret_cast<const f32x4*>(s)[i];
    u16x4 o;
    o.x = f2b(v.x); o.y = f2b(v.y); o.z = f2b(v.z); o.w = f2b(v.w);
    reinterpret_cast<u16x4*>(d)[i] = o;
  }
}

// ---------------- bf16 B^T GEMM, 256x256 tile, 8-wave, pipelined phases ----------------
// C[m,n] = sum_k A[m,k]*B[n,k] + bias[n]
// (unchanged from round 2 — at the K=1024 plain-HIP structure ceiling ~860 TF)
template<int EPI>
__global__ __launch_bounds__(512, 2)
void gemm_bt(const unsigned short* __restrict__ A,
             const unsigned short* __restrict__ B,
             const float* __restrict__ bias,
             void* __restrict__ Cout,
             const int nTilesN) {
  __shared__ __align__(16) unsigned short lds[2 * 2 * 256 * 64]; // 128 KiB

  const int nwg = gridDim.x;
  const int bid = blockIdx.x;
  const int cpx = nwg >> 3;                       // nwg % 8 == 0 (4704 / 1568)
  const int swz = (bid & 7) * cpx + (bid >> 3);   // XCD-contiguous chunks (T1)
  const int mt = swz / nTilesN;
  const int nt = swz - mt * nTilesN;
  const long mBase = (long)mt * 256;
  const int nBase = nt * 256;

  const int tid = threadIdx.x;
  const int lane = tid & 63;
  const int wid = tid >> 6;
  const int wr = wid >> 2;        // 0..1  (M half: 128 rows)
  const int wc = wid & 3;         // 0..3  (N quarter: 64 cols)
  const int lr = lane & 15;
  const int kg = lane >> 4;       // 0..3

  const int rbase = tid >> 3;                          // 0..63
  const int c8 = (((tid & 7) ^ (rbase & 7)) << 3);     // shorts
  const unsigned short* aSrc = A + (size_t)(mBase + rbase) * KDIM + c8;
  const unsigned short* bSrc = B + (size_t)(nBase + rbase) * KDIM + c8;
  char* ldsB = (char*)lds;

  f32x4 acc[8][4] = {};

  const int aRow = (wr * 128 + lr) * 64;
  const int bRow = (wc * 64 + lr) * 64;
  const int fOff0 = ((0 * 4 + kg) ^ (lr & 7)) << 3;
  const int fOff1 = ((1 * 4 + kg) ^ (lr & 7)) << 3;

#define STAGE(buf, kt) do {                                         \
    char* dA = ldsB + (buf) * 65536 + tid * 16;                     \
    const unsigned short* sA = aSrc + (kt) * 64;                    \
    const unsigned short* sB = bSrc + (kt) * 64;                    \
    _Pragma("unroll")                                               \
    for (int j = 0; j < 4; ++j)                                     \
      gload16(sA + (size_t)j * 64 * KDIM, dA + j * 8192);           \
    _Pragma("unroll")                                               \
    for (int j = 0; j < 4; ++j)                                     \
      gload16(sB + (size_t)j * 64 * KDIM, dA + 32768 + j * 8192);   \
  } while (0)

  STAGE(0, 0);
  STAGE(1, 1);
  asm volatile("s_waitcnt vmcnt(8)" ::: "memory");
  __builtin_amdgcn_sched_barrier(0);
  bar();

  for (int kt = 0; kt < KDIM / 64; ++kt) {
    const int cb = kt & 1;
    const unsigned short* As = lds + cb * 32768;
    const unsigned short* Bs = As + 16384;

    bf16x8 a0[4], a1[4], a2[4], a3[4], b0[4], b1[4];

#pragma unroll
    for (int j = 0; j < 4; ++j)
      a0[j] = *reinterpret_cast<const bf16x8*>(As + aRow + j * 1024 + fOff0);
#pragma unroll
    for (int n = 0; n < 4; ++n)
      b0[n] = *reinterpret_cast<const bf16x8*>(Bs + bRow + n * 1024 + fOff0);

    __builtin_amdgcn_s_setprio(1);
#pragma unroll
    for (int j = 0; j < 4; ++j)
      a1[j] = *reinterpret_cast<const bf16x8*>(As + aRow + (4 + j) * 1024 + fOff0);
#pragma unroll
    for (int j = 0; j < 4; ++j)
#pragma unroll
      for (int n = 0; n < 4; ++n)
        acc[j][n] = __builtin_amdgcn_mfma_f32_16x16x32_bf16(
            a0[j], b0[n], acc[j][n], 0, 0, 0);
    __builtin_amdgcn_s_setprio(0);
    bar();

    __builtin_amdgcn_s_setprio(1);
#pragma unroll
    for (int j = 0; j < 4; ++j)
      a2[j] = *reinterpret_cast<const bf16x8*>(As + aRow + j * 1024 + fOff1);
#pragma unroll
    for (int n = 0; n < 4; ++n)
      b1[n] = *reinterpret_cast<const bf16x8*>(Bs + bRow + n * 1024 + fOff1);
#pragma unroll
    for (int j = 0; j < 4; ++j)
#pragma unroll
      for (int n = 0; n < 4; ++n)
        acc[4 + j][n] = __builtin_amdgcn_mfma_f32_16x16x32_bf16(
            a1[j], b0[n], acc[4 + j][n], 0, 0, 0);
    __builtin_amdgcn_s_setprio(0);
    bar();

    __builtin_amdgcn_s_setprio(1);
#pragma unroll
    for (int j = 0; j < 4; ++j)
      a3[j] = *reinterpret_cast<const bf16x8*>(As + aRow + (4 + j) * 1024 + fOff1);
#pragma unroll
    for (int j = 0; j < 4; ++j)
#pragma unroll
      for (int n = 0; n < 4; ++n)
        acc[j][n] = __builtin_amdgcn_mfma_f32_16x16x32_bf16(
            a2[j], b1[n], acc[j][n], 0, 0, 0);
    __builtin_amdgcn_s_setprio(0);
    bar();

    __builtin_amdgcn_s_setprio(1);
#pragma unroll
    for (int j = 0; j < 4; ++j)
#pragma unroll
      for (int n = 0; n < 4; ++n)
        acc[4 + j][n] = __builtin_amdgcn_mfma_f32_16x16x32_bf16(
            a3[j], b1[n], acc[4 + j][n], 0, 0, 0);
    __builtin_amdgcn_s_setprio(0);
    bar();

    if (kt < KDIM / 64 - 2) {
      STAGE(cb, kt + 2);
      asm volatile("s_waitcnt vmcnt(8)" ::: "memory");
      __builtin_amdgcn_sched_barrier(0);
      bar();
    } else if (kt == KDIM / 64 - 2) {
      asm volatile("s_waitcnt vmcnt(0)" ::: "memory");
      __builtin_amdgcn_sched_barrier(0);
      bar();
    }
  }
#undef STAGE

  if (EPI == 0) {
    unsigned short* qkvbuf = (unsigned short*)Cout;
#pragma unroll
    for (int m = 0; m < 8; ++m) {
      const int row0 = wr * 128 + m * 16 + kg * 4;
#pragma unroll
      for (int n = 0; n < 4; ++n) {
        const int col = nBase + wc * 64 + n * 16 + lr;
        const int which = col >> 10;
        const int head = (col >> 6) & 15;
        const int d = col & 63;
        const float bv = bias[col];
#pragma unroll
        for (int r = 0; r < 4; ++r) {
          const int gm = (int)mBase + row0 + r;
          const int w = gm / NT;
          const int t = gm - w * NT;
          float v = acc[m][n][r] + bv;
          if (which == 0) v *= 0.125f;
          qkvbuf[(((size_t)w * 3 + which) * HEADS + head) * NTOK + t * HD + d] =
              f2b(v);
        }
      }
    }
  } else {
    float* out = (float*)Cout;
#pragma unroll
    for (int m = 0; m < 8; ++m) {
      const int row0 = wr * 128 + m * 16 + kg * 4;
#pragma unroll
      for (int n = 0; n < 4; ++n) {
        const int col = nBase + wc * 64 + n * 16 + lr;
        const float bv = bias[col];
#pragma unroll
        for (int r = 0; r < 4; ++r) {
          const int gm = (int)mBase + row0 + r;
          out[(size_t)gm * KDIM + col] = acc[m][n][r] + bv;
        }
      }
    }
  }
}

// ---------------- window attention: 4 waves per (window, head) ----------------
// Wave wv handles Q-rows [16wv, 16wv+16). V in LDS shared by the block's 4
// waves (one __syncthreads after staging); P rows are per-wave-owned (wave wv
// writes rows 16wv..16wv+15 and reads only those back -> no barrier needed).
// LDS 17.9 KiB / 4 waves -> 8 blocks/CU = 32 waves/CU (was 8 waves/CU).
#define PSTR 72   // P LDS stride (elements), 16B-aligned rows
#define VSTR 68   // V LDS stride (elements), 8B-aligned rows

__global__ __launch_bounds__(256, 8)
void attn_mfma(const unsigned short* __restrict__ qkv,
               const float* __restrict__ mask,
               const float* __restrict__ bias_table,
               unsigned short* __restrict__ aout) {
  const int blk = blockIdx.x;
  const int w = blk >> 4;
  const int h = blk & 15;
  const int tid = threadIdx.x;
  const int lane = tid & 63;
  const int wv = tid >> 6;        // 0..3: Q-row quarter
  const int lr = lane & 15;
  const int kg = lane >> 4;

  __shared__ __align__(16) unsigned short Plds[64 * PSTR];
  __shared__ __align__(16) unsigned short Vlds[64 * VSTR];

  const unsigned short* qp = qkv + (((size_t)w * 3 + 0) * HEADS + h) * NTOK;
  const unsigned short* kp = qp + (size_t)HEADS * NTOK;
  const unsigned short* vp = qp + (size_t)2 * HEADS * NTOK;
  const float* mrow = mask + (size_t)(w & 63) * (NT * NT);

  // ---- stage V into LDS (rows t<49) cooperatively, zero pad rows 49..63 ----
#pragma unroll
  for (int i = 0; i < 4; ++i) {
    const int idx = i * 256 + tid;          // u16x4 chunk index, 784 total
    if (idx < 784) {
      const int t = idx >> 4, c4 = (idx & 15) * 4;
      u16x4 vv = *reinterpret_cast<const u16x4*>(vp + t * HD + c4);
      *reinterpret_cast<u16x4*>(&Vlds[t * VSTR + c4]) = vv;
    }
  }
  {
    unsigned int* z = reinterpret_cast<unsigned int*>(&Vlds[49 * VSTR]);
#pragma unroll
    for (int i = 0; i < 2; ++i) {
      const int idx = i * 256 + tid;        // 15*68/2 = 510 words
      if (idx < 510) z[idx] = 0u;
    }
  }
  __syncthreads();   // V visible to all 4 waves before PV

  // ---- accumulator preload: rel-bias + window mask (C-in of QK^T) ----
  const int a0 = wv * 16 + kg * 4;          // this wave's 4 a-rows start
  f32x4 acc[4];
  {
#pragma unroll
    for (int r = 0; r < 4; ++r) {
      const int a = a0 + r;
      const int ia = a / 7, ja = a % 7;
#pragma unroll
      for (int n = 0; n < 4; ++n) {
        const int b = n * 16 + lr;
        const int ib = b / 7, jb = b % 7;
        float v;
        if (b >= NT) v = -1e30f;
        else if (a >= NT) v = 0.f;
        else v = bias_table[((ia - ib + 6) * 13 + (ja - jb + 6)) * HEADS + h]
               + mrow[a * NT + b];
        acc[n][r] = v;
      }
    }
  }

  // ---- QK^T: direct global fragment loads (1 Q-frag, 4 K-frags per ks) ----
  int qrow = wv * 16 + lr; if (qrow > 48) qrow = 48;
#pragma unroll
  for (int ks = 0; ks < 2; ++ks) {
    bf16x8 af = *reinterpret_cast<const bf16x8*>(qp + qrow * HD + ks * 32 + kg * 8);
#pragma unroll
    for (int n = 0; n < 4; ++n) {
      int row = n * 16 + lr; if (row > 48) row = 48;
      bf16x8 bfr = *reinterpret_cast<const bf16x8*>(kp + row * HD + ks * 32 + kg * 8);
      acc[n] = __builtin_amdgcn_mfma_f32_16x16x32_bf16(af, bfr, acc[n], 0, 0, 0);
    }
  }

  // ---- in-register softmax: row a lives in the 16 lanes sharing kg ----
#pragma unroll
  for (int r = 0; r < 4; ++r) {
    float mx = fmaxf(fmaxf(acc[0][r], acc[1][r]),
                     fmaxf(acc[2][r], acc[3][r]));
    mx = fmaxf(mx, __shfl_xor(mx, 1));
    mx = fmaxf(mx, __shfl_xor(mx, 2));
    mx = fmaxf(mx, __shfl_xor(mx, 4));
    mx = fmaxf(mx, __shfl_xor(mx, 8));
    float s = 0.f;
#pragma unroll
    for (int n = 0; n < 4; ++n) {
      const float e = __expf(acc[n][r] - mx);
      acc[n][r] = e;
      s += e;
    }
    s += __shfl_xor(s, 1);
    s += __shfl_xor(s, 2);
    s += __shfl_xor(s, 4);
    s += __shfl_xor(s, 8);
    const float si = 1.0f / s;
#pragma unroll
    for (int n = 0; n < 4; ++n) acc[n][r] *= si;
  }

  // ---- P (normalized, bf16) -> own rows of Plds (same-wave write->read) ----
#pragma unroll
  for (int n = 0; n < 4; ++n)
#pragma unroll
    for (int r = 0; r < 4; ++r)
      Plds[(a0 + r) * PSTR + n * 16 + lr] = f2b(acc[n][r]);

  // ---- PV: A = own P rows (LDS b128), B = V^T (LDS scalar column reads) ----
  f32x4 acc2[4] = {};
  const int prow = wv * 16 + lr;
#pragma unroll
  for (int ks = 0; ks < 2; ++ks) {
    bf16x8 pf = *reinterpret_cast<const bf16x8*>(
        &Plds[prow * PSTR + ks * 32 + kg * 8]);
#pragma unroll
    for (int n = 0; n < 4; ++n) {
      union { bf16x8 v; unsigned short u[8]; } vu;
#pragma unroll
      for (int j = 0; j < 8; ++j)
        vu.u[j] = Vlds[(ks * 32 + kg * 8 + j) * VSTR + n * 16 + lr];
      acc2[n] = __builtin_amdgcn_mfma_f32_16x16x32_bf16(pf, vu.v, acc2[n], 0, 0, 0);
    }
  }

  // ---- store O rows a<49, bf16 [w*49+a][h*64+d] ----
#pragma unroll
  for (int r = 0; r < 4; ++r) {
    const int a = a0 + r;
    if (a >= NT) continue;
#pragma unroll
    for (int n = 0; n < 4; ++n) {
      const int d = n * 16 + lr;
      aout[((size_t)(w * NT + a)) * KDIM + h * HD + d] = f2b(acc2[n][r]);
    }
  }
}

extern "C" void kernel_launch(void* const* d_in, const int* in_sizes, int n_in,
                              void* d_out, int out_size, void* d_ws, size_t ws_size,
                              hipStream_t stream) {
  const float* x          = (const float*)d_in[0];
  const float* attn_mask  = (const float*)d_in[1];
  const float* qkv_w      = (const float*)d_in[2];
  const float* qkv_b      = (const float*)d_in[3];
  const float* proj_w     = (const float*)d_in[4];
  const float* proj_b     = (const float*)d_in[5];
  const float* bias_table = (const float*)d_in[6];
  float* out = (float*)d_out;

  char* ws = (char*)d_ws;
  const size_t xbf_bytes = (size_t)MROWS * KDIM * 2;
  unsigned short* xbf      = (unsigned short*)ws;
  unsigned short* qkvw_bf  = (unsigned short*)(ws + xbf_bytes);
  unsigned short* projw_bf = qkvw_bf + 3072 * 1024;
  unsigned short* qkvbuf   = (unsigned short*)(ws + xbf_bytes + 8388608);
  unsigned short* aout     = xbf;  // x_bf16 dead after QKV GEMM; reuse

  cvt_f32_bf16<<<8192, 256, 0, stream>>>(x, xbf, (long)MROWS * KDIM / 4);
  cvt_f32_bf16<<<3072, 256, 0, stream>>>(qkv_w, qkvw_bf, (long)3072 * 1024 / 4);
  cvt_f32_bf16<<<1024, 256, 0, stream>>>(proj_w, projw_bf, (long)1024 * 1024 / 4);

  // 256x256 tiles: M tiles = 100352/256 = 392
  gemm_bt<0><<<392 * 12, 512, 0, stream>>>(xbf, qkvw_bf, qkv_b, (void*)qkvbuf, 12);

  attn_mfma<<<2048 * HEADS, 256, 0, stream>>>(qkvbuf, attn_mask, bias_table, aout);

  gemm_bt<1><<<392 * 4, 512, 0, stream>>>(aout, projw_bf, proj_b, (void*)out, 4);
}

// Round 4
// 1497.643 us; speedup vs baseline: 1.1086x; 1.0076x over previous
//
#include <hip/hip_runtime.h>
#include <hip/hip_bf16.h>
#include <cstdint>
#include <cstddef>

#define HEADS 16
#define HD 64
#define NT 49
#define NTOK 3136          // NT*HD
#define MROWS 100352       // 2048*49
#define KDIM 1024

typedef __attribute__((ext_vector_type(4))) float f32x4;
typedef __attribute__((ext_vector_type(8))) short bf16x8;
typedef __attribute__((ext_vector_type(4))) unsigned short u16x4;

__device__ __forceinline__ unsigned short f2b(float f) {
  __hip_bfloat16 h = __float2bfloat16(f);
  return *reinterpret_cast<unsigned short*>(&h);
}
__device__ __forceinline__ float b2f(unsigned short u) {
  union { unsigned int i; float f; } c; c.i = ((unsigned int)u) << 16; return c.f;
}

__device__ __forceinline__ void gload16(const unsigned short* g, void* l) {
  __builtin_amdgcn_global_load_lds(
      (const __attribute__((address_space(1))) void*)g,
      (__attribute__((address_space(3))) void*)l, 16, 0, 0);
}

__device__ __forceinline__ void bar() {
  asm volatile("" ::: "memory");
  __builtin_amdgcn_s_barrier();
  asm volatile("" ::: "memory");
}

// ---------------- fp32 -> bf16 convert ----------------
__global__ void cvt_f32_bf16(const float* __restrict__ s,
                             unsigned short* __restrict__ d, long n4) {
  long stride = (long)gridDim.x * blockDim.x;
  for (long i = blockIdx.x * (long)blockDim.x + threadIdx.x; i < n4; i += stride) {
    f32x4 v = reinterpret_cast<const f32x4*>(s)[i];
    u16x4 o;
    o.x = f2b(v.x); o.y = f2b(v.y); o.z = f2b(v.z); o.w = f2b(v.w);
    reinterpret_cast<u16x4*>(d)[i] = o;
  }
}

// ---------------- bf16 B^T GEMM, 256x256 tile, 8-wave, pipelined phases ----------------
// C[m,n] = sum_k A[m,k]*B[n,k] + bias[n]
// (unchanged — at the K=1024 plain-HIP structure ceiling ~860 TF, m248 ref 848)
template<int EPI>
__global__ __launch_bounds__(512, 2)
void gemm_bt(const unsigned short* __restrict__ A,
             const unsigned short* __restrict__ B,
             const float* __restrict__ bias,
             void* __restrict__ Cout,
             const int nTilesN) {
  __shared__ __align__(16) unsigned short lds[2 * 2 * 256 * 64]; // 128 KiB

  const int nwg = gridDim.x;
  const int bid = blockIdx.x;
  const int cpx = nwg >> 3;                       // nwg % 8 == 0 (4704 / 1568)
  const int swz = (bid & 7) * cpx + (bid >> 3);   // XCD-contiguous chunks (T1)
  const int mt = swz / nTilesN;
  const int nt = swz - mt * nTilesN;
  const long mBase = (long)mt * 256;
  const int nBase = nt * 256;

  const int tid = threadIdx.x;
  const int lane = tid & 63;
  const int wid = tid >> 6;
  const int wr = wid >> 2;        // 0..1  (M half: 128 rows)
  const int wc = wid & 3;         // 0..3  (N quarter: 64 cols)
  const int lr = lane & 15;
  const int kg = lane >> 4;       // 0..3

  const int rbase = tid >> 3;                          // 0..63
  const int c8 = (((tid & 7) ^ (rbase & 7)) << 3);     // shorts
  const unsigned short* aSrc = A + (size_t)(mBase + rbase) * KDIM + c8;
  const unsigned short* bSrc = B + (size_t)(nBase + rbase) * KDIM + c8;
  char* ldsB = (char*)lds;

  f32x4 acc[8][4] = {};

  const int aRow = (wr * 128 + lr) * 64;
  const int bRow = (wc * 64 + lr) * 64;
  const int fOff0 = ((0 * 4 + kg) ^ (lr & 7)) << 3;
  const int fOff1 = ((1 * 4 + kg) ^ (lr & 7)) << 3;

#define STAGE(buf, kt) do {                                         \
    char* dA = ldsB + (buf) * 65536 + tid * 16;                     \
    const unsigned short* sA = aSrc + (kt) * 64;                    \
    const unsigned short* sB = bSrc + (kt) * 64;                    \
    _Pragma("unroll")                                               \
    for (int j = 0; j < 4; ++j)                                     \
      gload16(sA + (size_t)j * 64 * KDIM, dA + j * 8192);           \
    _Pragma("unroll")                                               \
    for (int j = 0; j < 4; ++j)                                     \
      gload16(sB + (size_t)j * 64 * KDIM, dA + 32768 + j * 8192);   \
  } while (0)

  STAGE(0, 0);
  STAGE(1, 1);
  asm volatile("s_waitcnt vmcnt(8)" ::: "memory");
  __builtin_amdgcn_sched_barrier(0);
  bar();

  for (int kt = 0; kt < KDIM / 64; ++kt) {
    const int cb = kt & 1;
    const unsigned short* As = lds + cb * 32768;
    const unsigned short* Bs = As + 16384;

    bf16x8 a0[4], a1[4], a2[4], a3[4], b0[4], b1[4];

#pragma unroll
    for (int j = 0; j < 4; ++j)
      a0[j] = *reinterpret_cast<const bf16x8*>(As + aRow + j * 1024 + fOff0);
#pragma unroll
    for (int n = 0; n < 4; ++n)
      b0[n] = *reinterpret_cast<const bf16x8*>(Bs + bRow + n * 1024 + fOff0);

    __builtin_amdgcn_s_setprio(1);
#pragma unroll
    for (int j = 0; j < 4; ++j)
      a1[j] = *reinterpret_cast<const bf16x8*>(As + aRow + (4 + j) * 1024 + fOff0);
#pragma unroll
    for (int j = 0; j < 4; ++j)
#pragma unroll
      for (int n = 0; n < 4; ++n)
        acc[j][n] = __builtin_amdgcn_mfma_f32_16x16x32_bf16(
            a0[j], b0[n], acc[j][n], 0, 0, 0);
    __builtin_amdgcn_s_setprio(0);
    bar();

    __builtin_amdgcn_s_setprio(1);
#pragma unroll
    for (int j = 0; j < 4; ++j)
      a2[j] = *reinterpret_cast<const bf16x8*>(As + aRow + j * 1024 + fOff1);
#pragma unroll
    for (int n = 0; n < 4; ++n)
      b1[n] = *reinterpret_cast<const bf16x8*>(Bs + bRow + n * 1024 + fOff1);
#pragma unroll
    for (int j = 0; j < 4; ++j)
#pragma unroll
      for (int n = 0; n < 4; ++n)
        acc[4 + j][n] = __builtin_amdgcn_mfma_f32_16x16x32_bf16(
            a1[j], b0[n], acc[4 + j][n], 0, 0, 0);
    __builtin_amdgcn_s_setprio(0);
    bar();

    __builtin_amdgcn_s_setprio(1);
#pragma unroll
    for (int j = 0; j < 4; ++j)
      a3[j] = *reinterpret_cast<const bf16x8*>(As + aRow + (4 + j) * 1024 + fOff1);
#pragma unroll
    for (int j = 0; j < 4; ++j)
#pragma unroll
      for (int n = 0; n < 4; ++n)
        acc[j][n] = __builtin_amdgcn_mfma_f32_16x16x32_bf16(
            a2[j], b1[n], acc[j][n], 0, 0, 0);
    __builtin_amdgcn_s_setprio(0);
    bar();

    __builtin_amdgcn_s_setprio(1);
#pragma unroll
    for (int j = 0; j < 4; ++j)
#pragma unroll
      for (int n = 0; n < 4; ++n)
        acc[4 + j][n] = __builtin_amdgcn_mfma_f32_16x16x32_bf16(
            a3[j], b1[n], acc[4 + j][n], 0, 0, 0);
    __builtin_amdgcn_s_setprio(0);
    bar();

    if (kt < KDIM / 64 - 2) {
      STAGE(cb, kt + 2);
      asm volatile("s_waitcnt vmcnt(8)" ::: "memory");
      __builtin_amdgcn_sched_barrier(0);
      bar();
    } else if (kt == KDIM / 64 - 2) {
      asm volatile("s_waitcnt vmcnt(0)" ::: "memory");
      __builtin_amdgcn_sched_barrier(0);
      bar();
    }
  }
#undef STAGE

  if (EPI == 0) {
    unsigned short* qkvbuf = (unsigned short*)Cout;
#pragma unroll
    for (int m = 0; m < 8; ++m) {
      const int row0 = wr * 128 + m * 16 + kg * 4;
#pragma unroll
      for (int n = 0; n < 4; ++n) {
        const int col = nBase + wc * 64 + n * 16 + lr;
        const int which = col >> 10;
        const int head = (col >> 6) & 15;
        const int d = col & 63;
        const float bv = bias[col];
#pragma unroll
        for (int r = 0; r < 4; ++r) {
          const int gm = (int)mBase + row0 + r;
          const int w = gm / NT;
          const int t = gm - w * NT;
          float v = acc[m][n][r] + bv;
          if (which == 0) v *= 0.125f;
          qkvbuf[(((size_t)w * 3 + which) * HEADS + head) * NTOK + t * HD + d] =
              f2b(v);
        }
      }
    }
  } else {
    float* out = (float*)Cout;
#pragma unroll
    for (int m = 0; m < 8; ++m) {
      const int row0 = wr * 128 + m * 16 + kg * 4;
#pragma unroll
      for (int n = 0; n < 4; ++n) {
        const int col = nBase + wc * 64 + n * 16 + lr;
        const float bv = bias[col];
#pragma unroll
        for (int r = 0; r < 4; ++r) {
          const int gm = (int)mBase + row0 + r;
          out[(size_t)gm * KDIM + col] = acc[m][n][r] + bv;
        }
      }
    }
  }
}

// ---------------- window attention: 4 waves per (window, head) ----------------
// Wave wv handles Q-rows [16wv, 16wv+16). V stored TRANSPOSED in LDS (V^T:
// row d, col t) with a T2 XOR swizzle on the 16B slot (slot ^= d&7, same
// involution on write and read) so PV's B-fragments are single ds_read_b128
// at 2-way (free) bank aliasing — replaces 64 scalar ds_read_u16 per thread.
// P rows are per-wave-owned (write->read same wave, no barrier).
#define PSTR 72   // P LDS stride (elements), 16B-aligned rows
#define VTSTR 72  // V^T LDS stride (elements): 8 data slots of 16B + 1 pad

__global__ __launch_bounds__(256, 8)
void attn_mfma(const unsigned short* __restrict__ qkv,
               const float* __restrict__ mask,
               const float* __restrict__ bias_table,
               unsigned short* __restrict__ aout) {
  const int blk = blockIdx.x;
  const int w = blk >> 4;
  const int h = blk & 15;
  const int tid = threadIdx.x;
  const int lane = tid & 63;
  const int wv = tid >> 6;        // 0..3: Q-row quarter
  const int lr = lane & 15;
  const int kg = lane >> 4;

  __shared__ __align__(16) unsigned short Plds[64 * PSTR];
  __shared__ __align__(16) unsigned short VldsT[64 * VTSTR];

  const unsigned short* qp = qkv + (((size_t)w * 3 + 0) * HEADS + h) * NTOK;
  const unsigned short* kp = qp + (size_t)HEADS * NTOK;
  const unsigned short* vp = qp + (size_t)2 * HEADS * NTOK;
  const float* mrow = mask + (size_t)(w & 63) * (NT * NT);

  // ---- stage V^T into LDS: VldsT[d][t] = V[t][d], swizzled slot ----
#pragma unroll
  for (int i = 0; i < 4; ++i) {
    const int idx = i * 256 + tid;          // u16x4 chunk index, 784 total
    if (idx < 784) {
      const int t = idx >> 4, c4 = (idx & 15) * 4;
      u16x4 vv = *reinterpret_cast<const u16x4*>(vp + t * HD + c4);
      const int ts = t >> 3, t7 = t & 7;
#pragma unroll
      for (int ii = 0; ii < 4; ++ii) {
        const int d = c4 + ii;
        VldsT[d * VTSTR + (((ts ^ (d & 7)) << 3) + t7)] =
            ((const unsigned short*)&vv)[ii];
      }
    }
  }
  // zero pad cols t=49..63 for all 64 d-rows (swizzled)
#pragma unroll
  for (int i = 0; i < 4; ++i) {
    const int idx = i * 256 + tid;          // 64*15 = 960
    if (idx < 960) {
      const int d = idx / 15, t = 49 + idx - d * 15;
      VldsT[d * VTSTR + ((((t >> 3) ^ (d & 7)) << 3) + (t & 7))] = 0;
    }
  }
  __syncthreads();   // V^T visible to all 4 waves before PV

  // ---- accumulator preload: rel-bias + window mask (C-in of QK^T) ----
  const int a0 = wv * 16 + kg * 4;          // this wave's 4 a-rows start
  f32x4 acc[4];
  {
#pragma unroll
    for (int r = 0; r < 4; ++r) {
      const int a = a0 + r;
      const int ia = a / 7, ja = a % 7;
#pragma unroll
      for (int n = 0; n < 4; ++n) {
        const int b = n * 16 + lr;
        const int ib = b / 7, jb = b % 7;
        float v;
        if (b >= NT) v = -1e30f;
        else if (a >= NT) v = 0.f;
        else v = bias_table[((ia - ib + 6) * 13 + (ja - jb + 6)) * HEADS + h]
               + mrow[a * NT + b];
        acc[n][r] = v;
      }
    }
  }

  // ---- QK^T: direct global fragment loads (1 Q-frag, 4 K-frags per ks) ----
  int qrow = wv * 16 + lr; if (qrow > 48) qrow = 48;
#pragma unroll
  for (int ks = 0; ks < 2; ++ks) {
    bf16x8 af = *reinterpret_cast<const bf16x8*>(qp + qrow * HD + ks * 32 + kg * 8);
#pragma unroll
    for (int n = 0; n < 4; ++n) {
      int row = n * 16 + lr; if (row > 48) row = 48;
      bf16x8 bfr = *reinterpret_cast<const bf16x8*>(kp + row * HD + ks * 32 + kg * 8);
      acc[n] = __builtin_amdgcn_mfma_f32_16x16x32_bf16(af, bfr, acc[n], 0, 0, 0);
    }
  }

  // ---- in-register softmax: row a lives in the 16 lanes sharing kg ----
#pragma unroll
  for (int r = 0; r < 4; ++r) {
    float mx = fmaxf(fmaxf(acc[0][r], acc[1][r]),
                     fmaxf(acc[2][r], acc[3][r]));
    mx = fmaxf(mx, __shfl_xor(mx, 1));
    mx = fmaxf(mx, __shfl_xor(mx, 2));
    mx = fmaxf(mx, __shfl_xor(mx, 4));
    mx = fmaxf(mx, __shfl_xor(mx, 8));
    float s = 0.f;
#pragma unroll
    for (int n = 0; n < 4; ++n) {
      const float e = __expf(acc[n][r] - mx);
      acc[n][r] = e;
      s += e;
    }
    s += __shfl_xor(s, 1);
    s += __shfl_xor(s, 2);
    s += __shfl_xor(s, 4);
    s += __shfl_xor(s, 8);
    const float si = 1.0f / s;
#pragma unroll
    for (int n = 0; n < 4; ++n) acc[n][r] *= si;
  }

  // ---- P (normalized, bf16) -> own rows of Plds (same-wave write->read) ----
#pragma unroll
  for (int n = 0; n < 4; ++n)
#pragma unroll
    for (int r = 0; r < 4; ++r)
      Plds[(a0 + r) * PSTR + n * 16 + lr] = f2b(acc[n][r]);

  // ---- PV: A = own P rows (b128), B = V^T rows (swizzled b128) ----
  f32x4 acc2[4] = {};
  const int prow = wv * 16 + lr;
#pragma unroll
  for (int ks = 0; ks < 2; ++ks) {
    bf16x8 pf = *reinterpret_cast<const bf16x8*>(
        &Plds[prow * PSTR + ks * 32 + kg * 8]);
#pragma unroll
    for (int n = 0; n < 4; ++n) {
      const int d = n * 16 + lr;
      bf16x8 vf = *reinterpret_cast<const bf16x8*>(
          &VldsT[d * VTSTR + ((((ks * 4 + kg) ^ (d & 7)) << 3))]);
      acc2[n] = __builtin_amdgcn_mfma_f32_16x16x32_bf16(pf, vf, acc2[n], 0, 0, 0);
    }
  }

  // ---- store O rows a<49, bf16 [w*49+a][h*64+d] ----
#pragma unroll
  for (int r = 0; r < 4; ++r) {
    const int a = a0 + r;
    if (a >= NT) continue;
#pragma unroll
    for (int n = 0; n < 4; ++n) {
      const int d = n * 16 + lr;
      aout[((size_t)(w * NT + a)) * KDIM + h * HD + d] = f2b(acc2[n][r]);
    }
  }
}

extern "C" void kernel_launch(void* const* d_in, const int* in_sizes, int n_in,
                              void* d_out, int out_size, void* d_ws, size_t ws_size,
                              hipStream_t stream) {
  const float* x          = (const float*)d_in[0];
  const float* attn_mask  = (const float*)d_in[1];
  const float* qkv_w      = (const float*)d_in[2];
  const float* qkv_b      = (const float*)d_in[3];
  const float* proj_w     = (const float*)d_in[4];
  const float* proj_b     = (const float*)d_in[5];
  const float* bias_table = (const float*)d_in[6];
  float* out = (float*)d_out;

  char* ws = (char*)d_ws;
  const size_t xbf_bytes = (size_t)MROWS * KDIM * 2;
  unsigned short* xbf      = (unsigned short*)ws;
  unsigned short* qkvw_bf  = (unsigned short*)(ws + xbf_bytes);
  unsigned short* projw_bf = qkvw_bf + 3072 * 1024;
  unsigned short* qkvbuf   = (unsigned short*)(ws + xbf_bytes + 8388608);
  unsigned short* aout     = xbf;  // x_bf16 dead after QKV GEMM; reuse

  cvt_f32_bf16<<<8192, 256, 0, stream>>>(x, xbf, (long)MROWS * KDIM / 4);
  cvt_f32_bf16<<<3072, 256, 0, stream>>>(qkv_w, qkvw_bf, (long)3072 * 1024 / 4);
  cvt_f32_bf16<<<1024, 256, 0, stream>>>(proj_w, projw_bf, (long)1024 * 1024 / 4);

  // 256x256 tiles: M tiles = 100352/256 = 392
  gemm_bt<0><<<392 * 12, 512, 0, stream>>>(xbf, qkvw_bf, qkv_b, (void*)qkvbuf, 12);

  attn_mfma<<<2048 * HEADS, 256, 0, stream>>>(qkvbuf, attn_mask, bias_table, aout);

  gemm_bt<1><<<392 * 4, 512, 0, stream>>>(aout, projw_bf, proj_b, (void*)out, 4);
}

// Round 5
// 1374.753 us; speedup vs baseline: 1.2077x; 1.0894x over previous
//
#include <hip/hip_runtime.h>
#include <hip/hip_bf16.h>
#include <cstdint>
#include <cstddef>

#define HEADS 16
#define HD 64
#define NT 49
#define NTOK 3136          // NT*HD
#define MROWS 100352       // 2048*49
#define KDIM 1024

typedef __attribute__((ext_vector_type(4))) float f32x4;
typedef __attribute__((ext_vector_type(8))) short bf16x8;
typedef __attribute__((ext_vector_type(4))) unsigned short u16x4;

__device__ __forceinline__ unsigned short f2b(float f) {
  __hip_bfloat16 h = __float2bfloat16(f);
  return *reinterpret_cast<unsigned short*>(&h);
}
__device__ __forceinline__ float b2f(unsigned short u) {
  union { unsigned int i; float f; } c; c.i = ((unsigned int)u) << 16; return c.f;
}

__device__ __forceinline__ void gload16(const unsigned short* g, void* l) {
  __builtin_amdgcn_global_load_lds(
      (const __attribute__((address_space(1))) void*)g,
      (__attribute__((address_space(3))) void*)l, 16, 0, 0);
}

__device__ __forceinline__ void bar() {
  asm volatile("" ::: "memory");
  __builtin_amdgcn_s_barrier();
  asm volatile("" ::: "memory");
}

// ---------------- fp32 -> bf16 convert ----------------
__global__ void cvt_f32_bf16(const float* __restrict__ s,
                             unsigned short* __restrict__ d, long n4) {
  long stride = (long)gridDim.x * blockDim.x;
  for (long i = blockIdx.x * (long)blockDim.x + threadIdx.x; i < n4; i += stride) {
    f32x4 v = reinterpret_cast<const f32x4*>(s)[i];
    u16x4 o;
    o.x = f2b(v.x); o.y = f2b(v.y); o.z = f2b(v.z); o.w = f2b(v.w);
    reinterpret_cast<u16x4*>(d)[i] = o;
  }
}

// ---------------- fused (window mask + rel-pos bias) logit table ----------------
// BM[wm][h][a][b] for a<49, b<64; b>=49 baked to -1e30. 64*16*49*64*4B = 12.8 MB.
// Does the div/mod + bias gather ONCE per (wm,h,a,b) instead of per attn block.
__global__ void build_bm(const float* __restrict__ mask,
                         const float* __restrict__ bias_table,
                         float* __restrict__ bm) {
  const int wm = blockIdx.x >> 4, h = blockIdx.x & 15;
  const float* mrow = mask + (size_t)wm * (NT * NT);
  float* dst = bm + ((size_t)wm * HEADS + h) * (NT * 64);
  for (int idx = threadIdx.x; idx < NT * 64; idx += 256) {
    const int a = idx >> 6, b = idx & 63;
    float v = -1e30f;
    if (b < NT) {
      const int ia = a / 7, ja = a - ia * 7;
      const int ib = b / 7, jb = b - ib * 7;
      v = mrow[a * NT + b] +
          bias_table[((ia - ib + 6) * 13 + (ja - jb + 6)) * HEADS + h];
    }
    dst[idx] = v;
  }
}

// ---------------- bf16 B^T GEMM, 256x256 tile, 8-wave, pipelined phases ----------------
// C[m,n] = sum_k A[m,k]*B[n,k] + bias[n]
// (unchanged — at the K=1024 plain-HIP structure ceiling ~865 TF, m248 ref 848)
template<int EPI>
__global__ __launch_bounds__(512, 2)
void gemm_bt(const unsigned short* __restrict__ A,
             const unsigned short* __restrict__ B,
             const float* __restrict__ bias,
             void* __restrict__ Cout,
             const int nTilesN) {
  __shared__ __align__(16) unsigned short lds[2 * 2 * 256 * 64]; // 128 KiB

  const int nwg = gridDim.x;
  const int bid = blockIdx.x;
  const int cpx = nwg >> 3;                       // nwg % 8 == 0 (4704 / 1568)
  const int swz = (bid & 7) * cpx + (bid >> 3);   // XCD-contiguous chunks (T1)
  const int mt = swz / nTilesN;
  const int nt = swz - mt * nTilesN;
  const long mBase = (long)mt * 256;
  const int nBase = nt * 256;

  const int tid = threadIdx.x;
  const int lane = tid & 63;
  const int wid = tid >> 6;
  const int wr = wid >> 2;        // 0..1  (M half: 128 rows)
  const int wc = wid & 3;         // 0..3  (N quarter: 64 cols)
  const int lr = lane & 15;
  const int kg = lane >> 4;       // 0..3

  const int rbase = tid >> 3;                          // 0..63
  const int c8 = (((tid & 7) ^ (rbase & 7)) << 3);     // shorts
  const unsigned short* aSrc = A + (size_t)(mBase + rbase) * KDIM + c8;
  const unsigned short* bSrc = B + (size_t)(nBase + rbase) * KDIM + c8;
  char* ldsB = (char*)lds;

  f32x4 acc[8][4] = {};

  const int aRow = (wr * 128 + lr) * 64;
  const int bRow = (wc * 64 + lr) * 64;
  const int fOff0 = ((0 * 4 + kg) ^ (lr & 7)) << 3;
  const int fOff1 = ((1 * 4 + kg) ^ (lr & 7)) << 3;

#define STAGE(buf, kt) do {                                         \
    char* dA = ldsB + (buf) * 65536 + tid * 16;                     \
    const unsigned short* sA = aSrc + (kt) * 64;                    \
    const unsigned short* sB = bSrc + (kt) * 64;                    \
    _Pragma("unroll")                                               \
    for (int j = 0; j < 4; ++j)                                     \
      gload16(sA + (size_t)j * 64 * KDIM, dA + j * 8192);           \
    _Pragma("unroll")                                               \
    for (int j = 0; j < 4; ++j)                                     \
      gload16(sB + (size_t)j * 64 * KDIM, dA + 32768 + j * 8192);   \
  } while (0)

  STAGE(0, 0);
  STAGE(1, 1);
  asm volatile("s_waitcnt vmcnt(8)" ::: "memory");
  __builtin_amdgcn_sched_barrier(0);
  bar();

  for (int kt = 0; kt < KDIM / 64; ++kt) {
    const int cb = kt & 1;
    const unsigned short* As = lds + cb * 32768;
    const unsigned short* Bs = As + 16384;

    bf16x8 a0[4], a1[4], a2[4], a3[4], b0[4], b1[4];

#pragma unroll
    for (int j = 0; j < 4; ++j)
      a0[j] = *reinterpret_cast<const bf16x8*>(As + aRow + j * 1024 + fOff0);
#pragma unroll
    for (int n = 0; n < 4; ++n)
      b0[n] = *reinterpret_cast<const bf16x8*>(Bs + bRow + n * 1024 + fOff0);

    __builtin_amdgcn_s_setprio(1);
#pragma unroll
    for (int j = 0; j < 4; ++j)
      a1[j] = *reinterpret_cast<const bf16x8*>(As + aRow + (4 + j) * 1024 + fOff0);
#pragma unroll
    for (int j = 0; j < 4; ++j)
#pragma unroll
      for (int n = 0; n < 4; ++n)
        acc[j][n] = __builtin_amdgcn_mfma_f32_16x16x32_bf16(
            a0[j], b0[n], acc[j][n], 0, 0, 0);
    __builtin_amdgcn_s_setprio(0);
    bar();

    __builtin_amdgcn_s_setprio(1);
#pragma unroll
    for (int j = 0; j < 4; ++j)
      a2[j] = *reinterpret_cast<const bf16x8*>(As + aRow + j * 1024 + fOff1);
#pragma unroll
    for (int n = 0; n < 4; ++n)
      b1[n] = *reinterpret_cast<const bf16x8*>(Bs + bRow + n * 1024 + fOff1);
#pragma unroll
    for (int j = 0; j < 4; ++j)
#pragma unroll
      for (int n = 0; n < 4; ++n)
        acc[4 + j][n] = __builtin_amdgcn_mfma_f32_16x16x32_bf16(
            a1[j], b0[n], acc[4 + j][n], 0, 0, 0);
    __builtin_amdgcn_s_setprio(0);
    bar();

    __builtin_amdgcn_s_setprio(1);
#pragma unroll
    for (int j = 0; j < 4; ++j)
      a3[j] = *reinterpret_cast<const bf16x8*>(As + aRow + (4 + j) * 1024 + fOff1);
#pragma unroll
    for (int j = 0; j < 4; ++j)
#pragma unroll
      for (int n = 0; n < 4; ++n)
        acc[j][n] = __builtin_amdgcn_mfma_f32_16x16x32_bf16(
            a2[j], b1[n], acc[j][n], 0, 0, 0);
    __builtin_amdgcn_s_setprio(0);
    bar();

    __builtin_amdgcn_s_setprio(1);
#pragma unroll
    for (int j = 0; j < 4; ++j)
#pragma unroll
      for (int n = 0; n < 4; ++n)
        acc[4 + j][n] = __builtin_amdgcn_mfma_f32_16x16x32_bf16(
            a3[j], b1[n], acc[4 + j][n], 0, 0, 0);
    __builtin_amdgcn_s_setprio(0);
    bar();

    if (kt < KDIM / 64 - 2) {
      STAGE(cb, kt + 2);
      asm volatile("s_waitcnt vmcnt(8)" ::: "memory");
      __builtin_amdgcn_sched_barrier(0);
      bar();
    } else if (kt == KDIM / 64 - 2) {
      asm volatile("s_waitcnt vmcnt(0)" ::: "memory");
      __builtin_amdgcn_sched_barrier(0);
      bar();
    }
  }
#undef STAGE

  if (EPI == 0) {
    unsigned short* qkvbuf = (unsigned short*)Cout;
#pragma unroll
    for (int m = 0; m < 8; ++m) {
      const int row0 = wr * 128 + m * 16 + kg * 4;
#pragma unroll
      for (int n = 0; n < 4; ++n) {
        const int col = nBase + wc * 64 + n * 16 + lr;
        const int which = col >> 10;
        const int head = (col >> 6) & 15;
        const int d = col & 63;
        const float bv = bias[col];
#pragma unroll
        for (int r = 0; r < 4; ++r) {
          const int gm = (int)mBase + row0 + r;
          const int w = gm / NT;
          const int t = gm - w * NT;
          float v = acc[m][n][r] + bv;
          if (which == 0) v *= 0.125f;
          qkvbuf[(((size_t)w * 3 + which) * HEADS + head) * NTOK + t * HD + d] =
              f2b(v);
        }
      }
    }
  } else {
    float* out = (float*)Cout;
#pragma unroll
    for (int m = 0; m < 8; ++m) {
      const int row0 = wr * 128 + m * 16 + kg * 4;
#pragma unroll
      for (int n = 0; n < 4; ++n) {
        const int col = nBase + wc * 64 + n * 16 + lr;
        const float bv = bias[col];
#pragma unroll
        for (int r = 0; r < 4; ++r) {
          const int gm = (int)mBase + row0 + r;
          out[(size_t)gm * KDIM + col] = acc[m][n][r] + bv;
        }
      }
    }
  }
}

// ---------------- window attention: 4 waves per (window, head) ----------------
// Wave wv handles Q-rows [16wv, 16wv+16). V stored TRANSPOSED in LDS (V^T)
// with T2 XOR swizzle (slot ^= d&7) so PV B-frags are single ds_read_b128.
// C-in logits come from the precomputed BM table (16 coalesced f32 loads,
// no div/mod, no bias gather). P rows per-wave-owned (no barrier).
#define PSTR 72   // P LDS stride (elements), 16B-aligned rows
#define VTSTR 72  // V^T LDS stride (elements): 8 data slots of 16B + 1 pad

__global__ __launch_bounds__(256, 8)
void attn_mfma(const unsigned short* __restrict__ qkv,
               const float* __restrict__ bm,
               unsigned short* __restrict__ aout) {
  const int blk = blockIdx.x;
  const int w = blk >> 4;
  const int h = blk & 15;
  const int tid = threadIdx.x;
  const int lane = tid & 63;
  const int wv = tid >> 6;        // 0..3: Q-row quarter
  const int lr = lane & 15;
  const int kg = lane >> 4;

  __shared__ __align__(16) unsigned short Plds[64 * PSTR];
  __shared__ __align__(16) unsigned short VldsT[64 * VTSTR];

  const unsigned short* qp = qkv + (((size_t)w * 3 + 0) * HEADS + h) * NTOK;
  const unsigned short* kp = qp + (size_t)HEADS * NTOK;
  const unsigned short* vp = qp + (size_t)2 * HEADS * NTOK;
  const float* bmrow = bm + (((size_t)(w & 63) * HEADS + h) * (NT * 64));

  // ---- accumulator preload from BM table (issued first; latency hides
  //      under V staging). Rows a>=49 read row 48 (outputs discarded). ----
  const int a0 = wv * 16 + kg * 4;          // this wave's 4 a-rows start
  f32x4 acc[4];
#pragma unroll
  for (int r = 0; r < 4; ++r) {
    const int a = a0 + r;
    const int ar = (a > 48) ? 48 : a;
#pragma unroll
    for (int n = 0; n < 4; ++n)
      acc[n][r] = bmrow[ar * 64 + n * 16 + lr];
  }

  // ---- stage V^T into LDS: VldsT[d][t] = V[t][d], swizzled slot ----
#pragma unroll
  for (int i = 0; i < 4; ++i) {
    const int idx = i * 256 + tid;          // u16x4 chunk index, 784 total
    if (idx < 784) {
      const int t = idx >> 4, c4 = (idx & 15) * 4;
      u16x4 vv = *reinterpret_cast<const u16x4*>(vp + t * HD + c4);
      const int ts = t >> 3, t7 = t & 7;
#pragma unroll
      for (int ii = 0; ii < 4; ++ii) {
        const int d = c4 + ii;
        VldsT[d * VTSTR + (((ts ^ (d & 7)) << 3) + t7)] =
            ((const unsigned short*)&vv)[ii];
      }
    }
  }
  // zero pad cols t=49..63 for all 64 d-rows (swizzled)
#pragma unroll
  for (int i = 0; i < 4; ++i) {
    const int idx = i * 256 + tid;          // 64*15 = 960
    if (idx < 960) {
      const int d = idx / 15, t = 49 + idx - d * 15;
      VldsT[d * VTSTR + ((((t >> 3) ^ (d & 7)) << 3) + (t & 7))] = 0;
    }
  }
  __syncthreads();   // V^T visible to all 4 waves before PV

  // ---- QK^T: direct global fragment loads (1 Q-frag, 4 K-frags per ks) ----
  int qrow = wv * 16 + lr; if (qrow > 48) qrow = 48;
#pragma unroll
  for (int ks = 0; ks < 2; ++ks) {
    bf16x8 af = *reinterpret_cast<const bf16x8*>(qp + qrow * HD + ks * 32 + kg * 8);
#pragma unroll
    for (int n = 0; n < 4; ++n) {
      int row = n * 16 + lr; if (row > 48) row = 48;
      bf16x8 bfr = *reinterpret_cast<const bf16x8*>(kp + row * HD + ks * 32 + kg * 8);
      acc[n] = __builtin_amdgcn_mfma_f32_16x16x32_bf16(af, bfr, acc[n], 0, 0, 0);
    }
  }

  // ---- in-register softmax: row a lives in the 16 lanes sharing kg ----
#pragma unroll
  for (int r = 0; r < 4; ++r) {
    float mx = fmaxf(fmaxf(acc[0][r], acc[1][r]),
                     fmaxf(acc[2][r], acc[3][r]));
    mx = fmaxf(mx, __shfl_xor(mx, 1));
    mx = fmaxf(mx, __shfl_xor(mx, 2));
    mx = fmaxf(mx, __shfl_xor(mx, 4));
    mx = fmaxf(mx, __shfl_xor(mx, 8));
    float s = 0.f;
#pragma unroll
    for (int n = 0; n < 4; ++n) {
      const float e = __expf(acc[n][r] - mx);
      acc[n][r] = e;
      s += e;
    }
    s += __shfl_xor(s, 1);
    s += __shfl_xor(s, 2);
    s += __shfl_xor(s, 4);
    s += __shfl_xor(s, 8);
    const float si = 1.0f / s;
#pragma unroll
    for (int n = 0; n < 4; ++n) acc[n][r] *= si;
  }

  // ---- P (normalized, bf16) -> own rows of Plds (same-wave write->read) ----
#pragma unroll
  for (int n = 0; n < 4; ++n)
#pragma unroll
    for (int r = 0; r < 4; ++r)
      Plds[(a0 + r) * PSTR + n * 16 + lr] = f2b(acc[n][r]);

  // ---- PV: A = own P rows (b128), B = V^T rows (swizzled b128) ----
  f32x4 acc2[4] = {};
  const int prow = wv * 16 + lr;
#pragma unroll
  for (int ks = 0; ks < 2; ++ks) {
    bf16x8 pf = *reinterpret_cast<const bf16x8*>(
        &Plds[prow * PSTR + ks * 32 + kg * 8]);
#pragma unroll
    for (int n = 0; n < 4; ++n) {
      const int d = n * 16 + lr;
      bf16x8 vf = *reinterpret_cast<const bf16x8*>(
          &VldsT[d * VTSTR + ((((ks * 4 + kg) ^ (d & 7)) << 3))]);
      acc2[n] = __builtin_amdgcn_mfma_f32_16x16x32_bf16(pf, vf, acc2[n], 0, 0, 0);
    }
  }

  // ---- store O rows a<49, bf16 [w*49+a][h*64+d] ----
#pragma unroll
  for (int r = 0; r < 4; ++r) {
    const int a = a0 + r;
    if (a >= NT) continue;
#pragma unroll
    for (int n = 0; n < 4; ++n) {
      const int d = n * 16 + lr;
      aout[((size_t)(w * NT + a)) * KDIM + h * HD + d] = f2b(acc2[n][r]);
    }
  }
}

extern "C" void kernel_launch(void* const* d_in, const int* in_sizes, int n_in,
                              void* d_out, int out_size, void* d_ws, size_t ws_size,
                              hipStream_t stream) {
  const float* x          = (const float*)d_in[0];
  const float* attn_mask  = (const float*)d_in[1];
  const float* qkv_w      = (const float*)d_in[2];
  const float* qkv_b      = (const float*)d_in[3];
  const float* proj_w     = (const float*)d_in[4];
  const float* proj_b     = (const float*)d_in[5];
  const float* bias_table = (const float*)d_in[6];
  float* out = (float*)d_out;

  char* ws = (char*)d_ws;
  const size_t xbf_bytes = (size_t)MROWS * KDIM * 2;                 // 205.5 MB
  const size_t qkv_bytes = (size_t)2048 * 3 * HEADS * NTOK * 2;      // 616.6 MB
  unsigned short* xbf      = (unsigned short*)ws;
  unsigned short* qkvw_bf  = (unsigned short*)(ws + xbf_bytes);
  unsigned short* projw_bf = qkvw_bf + 3072 * 1024;
  unsigned short* qkvbuf   = (unsigned short*)(ws + xbf_bytes + 8388608);
  float* bm                = (float*)(ws + xbf_bytes + 8388608 + qkv_bytes); // 12.8 MB
  unsigned short* aout     = xbf;  // x_bf16 dead after QKV GEMM; reuse

  build_bm<<<64 * HEADS, 256, 0, stream>>>(attn_mask, bias_table, bm);

  cvt_f32_bf16<<<8192, 256, 0, stream>>>(x, xbf, (long)MROWS * KDIM / 4);
  cvt_f32_bf16<<<3072, 256, 0, stream>>>(qkv_w, qkvw_bf, (long)3072 * 1024 / 4);
  cvt_f32_bf16<<<1024, 256, 0, stream>>>(proj_w, projw_bf, (long)1024 * 1024 / 4);

  // 256x256 tiles: M tiles = 100352/256 = 392
  gemm_bt<0><<<392 * 12, 512, 0, stream>>>(xbf, qkvw_bf, qkv_b, (void*)qkvbuf, 12);

  attn_mfma<<<2048 * HEADS, 256, 0, stream>>>(qkvbuf, bm, aout);

  gemm_bt<1><<<392 * 4, 512, 0, stream>>>(aout, projw_bf, proj_b, (void*)out, 4);
}

// Round 6
// 1359.566 us; speedup vs baseline: 1.2212x; 1.0112x over previous
//
#include <hip/hip_runtime.h>
#include <hip/hip_bf16.h>
#include <cstdint>
#include <cstddef>

#define HEADS 16
#define HD 64
#define NT 49
#define NTOK 3136          // NT*HD
#define MROWS 100352       // 2048*49
#define KDIM 1024

typedef __attribute__((ext_vector_type(4))) float f32x4;
typedef __attribute__((ext_vector_type(8))) short bf16x8;
typedef __attribute__((ext_vector_type(4))) unsigned short u16x4;

__device__ __forceinline__ unsigned short f2b(float f) {
  __hip_bfloat16 h = __float2bfloat16(f);
  return *reinterpret_cast<unsigned short*>(&h);
}
__device__ __forceinline__ float b2f(unsigned short u) {
  union { unsigned int i; float f; } c; c.i = ((unsigned int)u) << 16; return c.f;
}

__device__ __forceinline__ void gload16(const unsigned short* g, void* l) {
  __builtin_amdgcn_global_load_lds(
      (const __attribute__((address_space(1))) void*)g,
      (__attribute__((address_space(3))) void*)l, 16, 0, 0);
}

__device__ __forceinline__ void bar() {
  asm volatile("" ::: "memory");
  __builtin_amdgcn_s_barrier();
  asm volatile("" ::: "memory");
}

// ---------------- fp32 -> bf16 convert ----------------
__global__ void cvt_f32_bf16(const float* __restrict__ s,
                             unsigned short* __restrict__ d, long n4) {
  long stride = (long)gridDim.x * blockDim.x;
  for (long i = blockIdx.x * (long)blockDim.x + threadIdx.x; i < n4; i += stride) {
    f32x4 v = reinterpret_cast<const f32x4*>(s)[i];
    u16x4 o;
    o.x = f2b(v.x); o.y = f2b(v.y); o.z = f2b(v.z); o.w = f2b(v.w);
    reinterpret_cast<u16x4*>(d)[i] = o;
  }
}

// ---------------- fused (window mask + rel-pos bias) logit table ----------------
// BM[wm][h][a][b] for a<49, b<64; b>=49 baked to -1e30. 64*16*49*64*4B = 12.8 MB.
__global__ void build_bm(const float* __restrict__ mask,
                         const float* __restrict__ bias_table,
                         float* __restrict__ bm) {
  const int wm = blockIdx.x >> 4, h = blockIdx.x & 15;
  const float* mrow = mask + (size_t)wm * (NT * NT);
  float* dst = bm + ((size_t)wm * HEADS + h) * (NT * 64);
  for (int idx = threadIdx.x; idx < NT * 64; idx += 256) {
    const int a = idx >> 6, b = idx & 63;
    float v = -1e30f;
    if (b < NT) {
      const int ia = a / 7, ja = a - ia * 7;
      const int ib = b / 7, jb = b - ib * 7;
      v = mrow[a * NT + b] +
          bias_table[((ia - ib + 6) * 13 + (ja - jb + 6)) * HEADS + h];
    }
    dst[idx] = v;
  }
}

// ---------------- bf16 B^T GEMM, 256x128 tile, BK=32, 8-wave, 2 blocks/CU ----------------
// C[m,n] = sum_k A[m,k]*B[n,k] + bias[n]
// LDS: 2 dbuf x (A[256][32] + B[128][32]) bf16 = 48 KiB -> 2 blocks/CU,
// 16 waves/CU: cross-block overlap (m114) hides barrier/latency stalls.
// Swizzle: row has 4 16B slots; phys_slot = logical_slot ^ ((row>>1)&3)
// (involution; 2-way bank aliasing = free). Write side: linear LDS dest,
// pre-swizzled GLOBAL source column. Counted vmcnt(3), never 0 in loop.
template<int EPI>
__global__ __launch_bounds__(512, 4)
void gemm_bt(const unsigned short* __restrict__ A,
             const unsigned short* __restrict__ B,
             const float* __restrict__ bias,
             void* __restrict__ Cout,
             const int nTilesN) {
  __shared__ __align__(16) unsigned short lds[2 * 12288]; // 48 KiB

  const int nwg = gridDim.x;
  const int bid = blockIdx.x;
  const int cpx = nwg >> 3;                       // nwg % 8 == 0 (9408 / 3136)
  const int swz = (bid & 7) * cpx + (bid >> 3);   // XCD-contiguous chunks (T1)
  const int mt = swz / nTilesN;
  const int nt = swz - mt * nTilesN;
  const long mBase = (long)mt * 256;
  const int nBase = nt * 128;

  const int tid = threadIdx.x;
  const int lane = tid & 63;
  const int wid = tid >> 6;
  const int wr = wid >> 1;        // 0..3  (M quarter: 64 rows)
  const int wc = wid & 1;         // 0..1  (N half: 64 cols)
  const int lr = lane & 15;
  const int kg = lane >> 4;       // 0..3

  // staging: thread covers row (tid>>2), slot (tid&3); source col pre-swizzled
  const int srow = tid >> 2;                              // 0..127
  const int c8 = (((tid & 3) ^ ((tid >> 3) & 3)) << 3);   // shorts
  const unsigned short* aSrc0 = A + (size_t)(mBase + srow) * KDIM + c8;
  const unsigned short* aSrc1 = aSrc0 + (size_t)128 * KDIM; // f(row+128)==f(row)
  const unsigned short* bSrc  = B + (size_t)(nBase + srow) * KDIM + c8;
  char* ldsB = (char*)lds;

  f32x4 acc[4][4] = {};

  // fragment read offsets (shorts), swizzled: row*32 + (kg ^ ((row>>1)&3))*8
  int aOff[4], bOff[4];
#pragma unroll
  for (int m = 0; m < 4; ++m) {
    const int row = wr * 64 + m * 16 + lr;
    aOff[m] = row * 32 + ((kg ^ ((row >> 1) & 3)) << 3);
  }
#pragma unroll
  for (int n = 0; n < 4; ++n) {
    const int row = wc * 64 + n * 16 + lr;
    bOff[n] = row * 32 + ((kg ^ ((row >> 1) & 3)) << 3);
  }

#define STAGE(buf, kt) do {                               \
    char* dst = ldsB + (buf) * 24576 + tid * 16;          \
    gload16(aSrc0 + (kt) * 32, dst);                      \
    gload16(aSrc1 + (kt) * 32, dst + 8192);               \
    gload16(bSrc  + (kt) * 32, dst + 16384);              \
  } while (0)

  // prologue: tiles 0 and 1 in flight; wait tile 0 only (3 per tile per wave)
  STAGE(0, 0);
  STAGE(1, 1);
  asm volatile("s_waitcnt vmcnt(3)" ::: "memory");
  __builtin_amdgcn_sched_barrier(0);
  bar();

  for (int kt = 0; kt < KDIM / 32; ++kt) {
    const int cb = kt & 1;
    const unsigned short* As = lds + cb * 12288;
    const unsigned short* Bs = As + 8192;

    bf16x8 af[4], bfv[4];
#pragma unroll
    for (int m = 0; m < 4; ++m)
      af[m] = *reinterpret_cast<const bf16x8*>(As + aOff[m]);
#pragma unroll
    for (int n = 0; n < 4; ++n)
      bfv[n] = *reinterpret_cast<const bf16x8*>(Bs + bOff[n]);

    __builtin_amdgcn_s_setprio(1);
#pragma unroll
    for (int m = 0; m < 4; ++m)
#pragma unroll
      for (int n = 0; n < 4; ++n)
        acc[m][n] = __builtin_amdgcn_mfma_f32_16x16x32_bf16(
            af[m], bfv[n], acc[m][n], 0, 0, 0);
    __builtin_amdgcn_s_setprio(0);
    bar();   // MFMAs consumed this wave's reads; all waves done with buf cb

    if (kt < KDIM / 32 - 2) {
      STAGE(cb, kt + 2);
      asm volatile("s_waitcnt vmcnt(3)" ::: "memory");  // tile kt+1 landed
      __builtin_amdgcn_sched_barrier(0);
      bar();
    } else if (kt == KDIM / 32 - 2) {
      asm volatile("s_waitcnt vmcnt(0)" ::: "memory");  // drain last tile
      __builtin_amdgcn_sched_barrier(0);
      bar();
    }
  }
#undef STAGE

  if (EPI == 0) {
    unsigned short* qkvbuf = (unsigned short*)Cout;
#pragma unroll
    for (int m = 0; m < 4; ++m) {
      const int row0 = wr * 64 + m * 16 + kg * 4;
#pragma unroll
      for (int n = 0; n < 4; ++n) {
        const int col = nBase + wc * 64 + n * 16 + lr;
        const int which = col >> 10;
        const int head = (col >> 6) & 15;
        const int d = col & 63;
        const float bv = bias[col];
#pragma unroll
        for (int r = 0; r < 4; ++r) {
          const int gm = (int)mBase + row0 + r;
          const int w = gm / NT;
          const int t = gm - w * NT;
          float v = acc[m][n][r] + bv;
          if (which == 0) v *= 0.125f;
          qkvbuf[(((size_t)w * 3 + which) * HEADS + head) * NTOK + t * HD + d] =
              f2b(v);
        }
      }
    }
  } else {
    float* out = (float*)Cout;
#pragma unroll
    for (int m = 0; m < 4; ++m) {
      const int row0 = wr * 64 + m * 16 + kg * 4;
#pragma unroll
      for (int n = 0; n < 4; ++n) {
        const int col = nBase + wc * 64 + n * 16 + lr;
        const float bv = bias[col];
#pragma unroll
        for (int r = 0; r < 4; ++r) {
          const int gm = (int)mBase + row0 + r;
          out[(size_t)gm * KDIM + col] = acc[m][n][r] + bv;
        }
      }
    }
  }
}

// ---------------- window attention: 4 waves per (window, head) ----------------
// Wave wv handles Q-rows [16wv, 16wv+16). V stored TRANSPOSED in LDS (V^T)
// with T2 XOR swizzle (slot ^= d&7) so PV B-frags are single ds_read_b128.
// C-in logits come from the precomputed BM table (16 coalesced f32 loads,
// no div/mod, no bias gather). P rows per-wave-owned (no barrier).
#define PSTR 72   // P LDS stride (elements), 16B-aligned rows
#define VTSTR 72  // V^T LDS stride (elements): 8 data slots of 16B + 1 pad

__global__ __launch_bounds__(256, 8)
void attn_mfma(const unsigned short* __restrict__ qkv,
               const float* __restrict__ bm,
               unsigned short* __restrict__ aout) {
  const int blk = blockIdx.x;
  const int w = blk >> 4;
  const int h = blk & 15;
  const int tid = threadIdx.x;
  const int lane = tid & 63;
  const int wv = tid >> 6;        // 0..3: Q-row quarter
  const int lr = lane & 15;
  const int kg = lane >> 4;

  __shared__ __align__(16) unsigned short Plds[64 * PSTR];
  __shared__ __align__(16) unsigned short VldsT[64 * VTSTR];

  const unsigned short* qp = qkv + (((size_t)w * 3 + 0) * HEADS + h) * NTOK;
  const unsigned short* kp = qp + (size_t)HEADS * NTOK;
  const unsigned short* vp = qp + (size_t)2 * HEADS * NTOK;
  const float* bmrow = bm + (((size_t)(w & 63) * HEADS + h) * (NT * 64));

  // ---- accumulator preload from BM table (issued first; latency hides
  //      under V staging). Rows a>=49 read row 48 (outputs discarded). ----
  const int a0 = wv * 16 + kg * 4;          // this wave's 4 a-rows start
  f32x4 acc[4];
#pragma unroll
  for (int r = 0; r < 4; ++r) {
    const int a = a0 + r;
    const int ar = (a > 48) ? 48 : a;
#pragma unroll
    for (int n = 0; n < 4; ++n)
      acc[n][r] = bmrow[ar * 64 + n * 16 + lr];
  }

  // ---- stage V^T into LDS: VldsT[d][t] = V[t][d], swizzled slot ----
#pragma unroll
  for (int i = 0; i < 4; ++i) {
    const int idx = i * 256 + tid;          // u16x4 chunk index, 784 total
    if (idx < 784) {
      const int t = idx >> 4, c4 = (idx & 15) * 4;
      u16x4 vv = *reinterpret_cast<const u16x4*>(vp + t * HD + c4);
      const int ts = t >> 3, t7 = t & 7;
#pragma unroll
      for (int ii = 0; ii < 4; ++ii) {
        const int d = c4 + ii;
        VldsT[d * VTSTR + (((ts ^ (d & 7)) << 3) + t7)] =
            ((const unsigned short*)&vv)[ii];
      }
    }
  }
  // zero pad cols t=49..63 for all 64 d-rows (swizzled)
#pragma unroll
  for (int i = 0; i < 4; ++i) {
    const int idx = i * 256 + tid;          // 64*15 = 960
    if (idx < 960) {
      const int d = idx / 15, t = 49 + idx - d * 15;
      VldsT[d * VTSTR + ((((t >> 3) ^ (d & 7)) << 3) + (t & 7))] = 0;
    }
  }
  __syncthreads();   // V^T visible to all 4 waves before PV

  // ---- QK^T: direct global fragment loads (1 Q-frag, 4 K-frags per ks) ----
  int qrow = wv * 16 + lr; if (qrow > 48) qrow = 48;
#pragma unroll
  for (int ks = 0; ks < 2; ++ks) {
    bf16x8 af = *reinterpret_cast<const bf16x8*>(qp + qrow * HD + ks * 32 + kg * 8);
#pragma unroll
    for (int n = 0; n < 4; ++n) {
      int row = n * 16 + lr; if (row > 48) row = 48;
      bf16x8 bfr = *reinterpret_cast<const bf16x8*>(kp + row * HD + ks * 32 + kg * 8);
      acc[n] = __builtin_amdgcn_mfma_f32_16x16x32_bf16(af, bfr, acc[n], 0, 0, 0);
    }
  }

  // ---- in-register softmax: row a lives in the 16 lanes sharing kg ----
#pragma unroll
  for (int r = 0; r < 4; ++r) {
    float mx = fmaxf(fmaxf(acc[0][r], acc[1][r]),
                     fmaxf(acc[2][r], acc[3][r]));
    mx = fmaxf(mx, __shfl_xor(mx, 1));
    mx = fmaxf(mx, __shfl_xor(mx, 2));
    mx = fmaxf(mx, __shfl_xor(mx, 4));
    mx = fmaxf(mx, __shfl_xor(mx, 8));
    float s = 0.f;
#pragma unroll
    for (int n = 0; n < 4; ++n) {
      const float e = __expf(acc[n][r] - mx);
      acc[n][r] = e;
      s += e;
    }
    s += __shfl_xor(s, 1);
    s += __shfl_xor(s, 2);
    s += __shfl_xor(s, 4);
    s += __shfl_xor(s, 8);
    const float si = 1.0f / s;
#pragma unroll
    for (int n = 0; n < 4; ++n) acc[n][r] *= si;
  }

  // ---- P (normalized, bf16) -> own rows of Plds (same-wave write->read) ----
#pragma unroll
  for (int n = 0; n < 4; ++n)
#pragma unroll
    for (int r = 0; r < 4; ++r)
      Plds[(a0 + r) * PSTR + n * 16 + lr] = f2b(acc[n][r]);

  // ---- PV: A = own P rows (b128), B = V^T rows (swizzled b128) ----
  f32x4 acc2[4] = {};
  const int prow = wv * 16 + lr;
#pragma unroll
  for (int ks = 0; ks < 2; ++ks) {
    bf16x8 pf = *reinterpret_cast<const bf16x8*>(
        &Plds[prow * PSTR + ks * 32 + kg * 8]);
#pragma unroll
    for (int n = 0; n < 4; ++n) {
      const int d = n * 16 + lr;
      bf16x8 vf = *reinterpret_cast<const bf16x8*>(
          &VldsT[d * VTSTR + ((((ks * 4 + kg) ^ (d & 7)) << 3))]);
      acc2[n] = __builtin_amdgcn_mfma_f32_16x16x32_bf16(pf, vf, acc2[n], 0, 0, 0);
    }
  }

  // ---- store O rows a<49, bf16 [w*49+a][h*64+d] ----
#pragma unroll
  for (int r = 0; r < 4; ++r) {
    const int a = a0 + r;
    if (a >= NT) continue;
#pragma unroll
    for (int n = 0; n < 4; ++n) {
      const int d = n * 16 + lr;
      aout[((size_t)(w * NT + a)) * KDIM + h * HD + d] = f2b(acc2[n][r]);
    }
  }
}

extern "C" void kernel_launch(void* const* d_in, const int* in_sizes, int n_in,
                              void* d_out, int out_size, void* d_ws, size_t ws_size,
                              hipStream_t stream) {
  const float* x          = (const float*)d_in[0];
  const float* attn_mask  = (const float*)d_in[1];
  const float* qkv_w      = (const float*)d_in[2];
  const float* qkv_b      = (const float*)d_in[3];
  const float* proj_w     = (const float*)d_in[4];
  const float* proj_b     = (const float*)d_in[5];
  const float* bias_table = (const float*)d_in[6];
  float* out = (float*)d_out;

  char* ws = (char*)d_ws;
  const size_t xbf_bytes = (size_t)MROWS * KDIM * 2;                 // 205.5 MB
  const size_t qkv_bytes = (size_t)2048 * 3 * HEADS * NTOK * 2;      // 616.6 MB
  unsigned short* xbf      = (unsigned short*)ws;
  unsigned short* qkvw_bf  = (unsigned short*)(ws + xbf_bytes);
  unsigned short* projw_bf = qkvw_bf + 3072 * 1024;
  unsigned short* qkvbuf   = (unsigned short*)(ws + xbf_bytes + 8388608);
  float* bm                = (float*)(ws + xbf_bytes + 8388608 + qkv_bytes); // 12.8 MB
  unsigned short* aout     = xbf;  // x_bf16 dead after QKV GEMM; reuse

  build_bm<<<64 * HEADS, 256, 0, stream>>>(attn_mask, bias_table, bm);

  cvt_f32_bf16<<<8192, 256, 0, stream>>>(x, xbf, (long)MROWS * KDIM / 4);
  cvt_f32_bf16<<<3072, 256, 0, stream>>>(qkv_w, qkvw_bf, (long)3072 * 1024 / 4);
  cvt_f32_bf16<<<1024, 256, 0, stream>>>(proj_w, projw_bf, (long)1024 * 1024 / 4);

  // 256x128 tiles: M tiles = 392, N tiles = 24 (QKV) / 8 (proj)
  gemm_bt<0><<<392 * 24, 512, 0, stream>>>(xbf, qkvw_bf, qkv_b, (void*)qkvbuf, 24);

  attn_mfma<<<2048 * HEADS, 256, 0, stream>>>(qkvbuf, bm, aout);

  gemm_bt<1><<<392 * 8, 512, 0, stream>>>(aout, projw_bf, proj_b, (void*)out, 8);
}